// Round 7
// baseline (519.507 us; speedup 1.0000x reference)
//
#include <hip/hip_runtime.h>
#include <stdint.h>

// Cross-attention forward: B=2, N1=N2=2048, HID=768, 12 heads x 64.
// Round 7: flash reverted to register-only (no LDS/barriers, V inline) to
// cut VGPR below the 64 boundary (8 waves/SIMD) with NSPLIT=2 feeding it;
// exp2-folding (log2e into q-scale and mask prescale) removes the mul in
// every softmax exp. proj/attnw/prep structure unchanged otherwise.

typedef __attribute__((ext_vector_type(8))) short bf16x8;
typedef __attribute__((ext_vector_type(4))) short bf16x4;
typedef __attribute__((ext_vector_type(4))) float f32x4;

constexpr int B_  = 2;
constexpr int N_  = 2048;   // N1 == N2
constexpr int HID = 768;
constexpr int NH  = 12;
constexpr int HD  = 64;
constexpr int RS  = 144;    // proj LDS row stride bytes: 128 data + 16 pad
constexpr int NSPLIT = 2;
constexpr int KSPAN  = N_ / NSPLIT;
constexpr float L2E = 1.4426950408889634f;   // log2(e)

__device__ __forceinline__ short f2bf(float f) {   // RNE float->bf16
    uint32_t u = __builtin_bit_cast(uint32_t, f);
    u = (u + 0x7fffu + ((u >> 16) & 1u)) >> 16;
    return (short)u;
}

// ---------------------------------------------------------------------------
// P0a: X -> (hi|lo) bf16 rows of 1536; blocks >= 6144 prescale mask by log2e.
// ---------------------------------------------------------------------------
__global__ __launch_bounds__(256) void prep_x(
    const float* __restrict__ s1, const float* __restrict__ s2,
    const float* __restrict__ mask,
    short* __restrict__ X1, short* __restrict__ X2, float* __restrict__ mks)
{
    const int PT = (B_ * N_ * HID) / 4;
    if (blockIdx.x >= 6144) {
        const int idx = (blockIdx.x - 6144) * 256 + threadIdx.x;   // < 1024
        const float4 mv = *reinterpret_cast<const float4*>(&mask[idx * 4]);
        *reinterpret_cast<float4*>(&mks[idx * 4]) =
            make_float4(mv.x * L2E, mv.y * L2E, mv.z * L2E, mv.w * L2E);
        return;
    }
    int i = blockIdx.x * 256 + threadIdx.x;
    const float* S; short* X;
    if (i < PT) { S = s1; X = X1; } else { S = s2; X = X2; i -= PT; }
    const int e   = i * 4;
    const int row = e / HID;
    const int col = e - row * HID;
    const float4 v = *reinterpret_cast<const float4*>(&S[e]);
    float vs[4] = {v.x, v.y, v.z, v.w};
    short4 hi, lo;
    short* hp = &hi.x; short* lp = &lo.x;
    #pragma unroll
    for (int j = 0; j < 4; ++j) {
        const uint32_t u = __builtin_bit_cast(uint32_t, vs[j]);
        hp[j] = (short)(u >> 16);
        const float hif = __builtin_bit_cast(float, u & 0xffff0000u);
        lp[j] = f2bf(vs[j] - hif);
    }
    short* dst = X + (size_t)row * 1536 + col;
    *reinterpret_cast<short4*>(dst)       = hi;
    *reinterpret_cast<short4*>(dst + 768) = lo;
}

// ---------------------------------------------------------------------------
// P0b: W [k][n] fp32 -> WT [n][k] bf16 (3 matrices).  grid (12,12,3) x 256.
// ---------------------------------------------------------------------------
__global__ __launch_bounds__(256) void prep_w(
    const float* __restrict__ Wq, const float* __restrict__ Wk,
    const float* __restrict__ Wv, short* __restrict__ WT)
{
    const int z = blockIdx.z;
    const float* W = (z == 0) ? Wq : (z == 1) ? Wk : Wv;
    short* O = WT + (size_t)z * HID * HID;
    __shared__ short Tl[64][66];
    const int k0 = blockIdx.x * 64, n0 = blockIdx.y * 64;
    const int t = threadIdx.x;
    const int rr = t >> 4, cc = (t & 15) * 4;
    #pragma unroll
    for (int i = 0; i < 4; ++i) {
        const int row = i * 16 + rr;
        const float4 w = *reinterpret_cast<const float4*>(&W[(size_t)(k0 + row) * HID + n0 + cc]);
        Tl[cc + 0][row] = f2bf(w.x);
        Tl[cc + 1][row] = f2bf(w.y);
        Tl[cc + 2][row] = f2bf(w.z);
        Tl[cc + 3][row] = f2bf(w.w);
    }
    __syncthreads();
    #pragma unroll
    for (int i = 0; i < 4; ++i) {
        const int n = i * 16 + rr;
        short4 o;
        o.x = Tl[n][cc + 0]; o.y = Tl[n][cc + 1];
        o.z = Tl[n][cc + 2]; o.w = Tl[n][cc + 3];
        *reinterpret_cast<short4*>(&O[(size_t)(n0 + n) * HID + k0 + cc]) = o;
    }
}

// ---------------------------------------------------------------------------
// K1: proj GEMM (bf16 MFMA).  grid (32, 12, 3), block 256 (4 waves 2x2).
// Tile 128x64, BK=64. Reg-staged double-buffered padded LDS (RS=144).
// which=0: q*(0.125*log2e) -> qb; 1: k -> kbm; 2: v -> vtb [bh][d][n].
// ---------------------------------------------------------------------------
__global__ __launch_bounds__(256) void proj_mfma(
    const short* __restrict__ X1, const short* __restrict__ X2,
    const short* __restrict__ WT,
    const float* __restrict__ bq, const float* __restrict__ bk,
    const float* __restrict__ bv,
    short* __restrict__ qb, short* __restrict__ kbm, short* __restrict__ vtb)
{
    const int which = blockIdx.z;
    const char* Xb = (const char*)((which == 0) ? X1 : X2);        // row 3072 B
    const char* Wb = (const char*)(WT + (size_t)which * HID * HID); // row 1536 B
    const float* bias = (which == 0) ? bq : (which == 1) ? bk : bv;
    const int m0 = blockIdx.x * 128;
    const int n0 = blockIdx.y * 64;
    const int t = threadIdx.x;
    const int lane = t & 63;
    const int lg = lane >> 4, lm = lane & 15;
    const int wave = t >> 6;
    const int wr = wave >> 1, wc = wave & 1;

    __shared__ __align__(16) char Al[2][128 * RS];
    __shared__ __align__(16) char Bl[2][64 * RS];

    const int KSTEPS = (which == 2) ? 12 : 24;

    f32x4 acc[4][2];
    #pragma unroll
    for (int mt = 0; mt < 4; ++mt)
        #pragma unroll
        for (int nt = 0; nt < 2; ++nt) acc[mt][nt] = f32x4{0.f, 0.f, 0.f, 0.f};

    int4 ra[4], rb[2];
    auto loadAB = [&](int ks) {
        const int ka = ks * 128;
        const int kw = (ks % 12) * 128;
        #pragma unroll
        for (int u = 0; u < 4; ++u) {
            const int c = u * 256 + t;
            ra[u] = *reinterpret_cast<const int4*>(
                Xb + (size_t)(m0 + (c >> 3)) * 3072 + ka + (c & 7) * 16);
        }
        #pragma unroll
        for (int u = 0; u < 2; ++u) {
            const int c = u * 256 + t;
            rb[u] = *reinterpret_cast<const int4*>(
                Wb + (size_t)(n0 + (c >> 3)) * 1536 + kw + (c & 7) * 16);
        }
    };
    auto storeAB = [&](int buf) {
        #pragma unroll
        for (int u = 0; u < 4; ++u) {
            const int c = u * 256 + t;
            *reinterpret_cast<int4*>(&Al[buf][c * 16 + (c >> 3) * 16]) = ra[u];
        }
        #pragma unroll
        for (int u = 0; u < 2; ++u) {
            const int c = u * 256 + t;
            *reinterpret_cast<int4*>(&Bl[buf][c * 16 + (c >> 3) * 16]) = rb[u];
        }
    };

    loadAB(0);
    storeAB(0);
    __syncthreads();

    for (int ks = 0; ks < KSTEPS; ++ks) {
        const bool more = (ks + 1 < KSTEPS);
        if (more) loadAB(ks + 1);
        const char* Ab = Al[ks & 1];
        const char* Bb = Bl[ks & 1];
        #pragma unroll
        for (int ksub = 0; ksub < 2; ++ksub) {
            const int jj = ksub * 4 + lg;
            bf16x8 a[4], bb[2];
            #pragma unroll
            for (int mt = 0; mt < 4; ++mt) {
                const int r = wr * 64 + mt * 16 + lm;
                a[mt] = *reinterpret_cast<const bf16x8*>(Ab + r * RS + jj * 16);
            }
            #pragma unroll
            for (int nt = 0; nt < 2; ++nt) {
                const int r = wc * 32 + nt * 16 + lm;
                bb[nt] = *reinterpret_cast<const bf16x8*>(Bb + r * RS + jj * 16);
            }
            __builtin_amdgcn_s_setprio(1);
            #pragma unroll
            for (int mt = 0; mt < 4; ++mt)
                #pragma unroll
                for (int nt = 0; nt < 2; ++nt)
                    acc[mt][nt] = __builtin_amdgcn_mfma_f32_16x16x32_bf16(
                        a[mt], bb[nt], acc[mt][nt], 0, 0, 0);
            __builtin_amdgcn_s_setprio(0);
        }
        if (more) storeAB((ks + 1) & 1);
        __syncthreads();
    }

    const int b = m0 >> 11;
    const int head = blockIdx.y;
    const size_t bh = (size_t)(b * NH + head);

    if (which != 2) {
        const float sc = (which == 0) ? (0.125f * L2E) : 1.0f;  // q: fold 1/8*log2e
        short* dst = (which == 0) ? qb : kbm;
        #pragma unroll
        for (int mt = 0; mt < 4; ++mt)
            #pragma unroll
            for (int nt = 0; nt < 2; ++nt) {
                const int dd = wc * 32 + nt * 16 + lm;
                const float bi = bias[n0 + dd];
                #pragma unroll
                for (int r = 0; r < 4; ++r) {
                    const int m = m0 + wr * 64 + mt * 16 + 4 * lg + r;
                    const int n = m & 2047;
                    dst[(bh * N_ + n) * HD + dd] = f2bf((acc[mt][nt][r] + bi) * sc);
                }
            }
    } else {
        short* Ct = (short*)Al[0];
        #pragma unroll
        for (int mt = 0; mt < 4; ++mt)
            #pragma unroll
            for (int nt = 0; nt < 2; ++nt) {
                const int dd = wc * 32 + nt * 16 + lm;
                const float bi = bias[n0 + dd];
                #pragma unroll
                for (int r = 0; r < 4; ++r) {
                    const int ml = wr * 64 + mt * 16 + 4 * lg + r;
                    Ct[dd * 128 + ml] = f2bf(acc[mt][nt][r] + bi);
                }
            }
        __syncthreads();
        const int d = t >> 2, seg = t & 3;
        const short* src = Ct + d * 128 + seg * 32;
        short* dv = vtb + (bh * HD + d) * N_ + (m0 & 2047) + seg * 32;
        #pragma unroll
        for (int u = 0; u < 4; ++u)
            *reinterpret_cast<int4*>(dv + u * 8) = *reinterpret_cast<const int4*>(src + u * 8);
    }
}

// ---------------------------------------------------------------------------
// K2: split-K flash, register-only.  grid (N/64, NH, B*NSPLIT), block 256.
// Wave w owns q rows qt*64+w*16..+15; z = b*NSPLIT+s -> keys [s*KSPAN,...).
// No LDS, no barriers. Scores already in log2 units (q prescaled); exp2f.
// ---------------------------------------------------------------------------
__global__ __launch_bounds__(256) void flash_kernel(
    const short* __restrict__ qb, const short* __restrict__ kbm,
    const short* __restrict__ vtb, const float* __restrict__ mks,
    float* __restrict__ ctx0, float* __restrict__ ctx1,
    float* __restrict__ m_part, float* __restrict__ l_part)
{
    const int qt = blockIdx.x, h = blockIdx.y;
    const int b = blockIdx.z / NSPLIT, s = blockIdx.z % NSPLIT;
    const int lane = threadIdx.x & 63;
    const int wave = __builtin_amdgcn_readfirstlane(threadIdx.x >> 6);
    const int lg = lane >> 4, lm = lane & 15;
    const int q0 = qt * 64 + wave * 16;
    const int kstart = s * KSPAN;

    const size_t bh = (size_t)(b * NH + h);
    const short* qp = qb  + (bh * N_ + q0) * HD;
    const short* kp = kbm + bh * N_ * HD;
    const short* vp = vtb + bh * HD * N_;
    const float* mk = mks + (size_t)b * N_;

    const bf16x8 qf0 = *reinterpret_cast<const bf16x8*>(qp + lm * HD + lg * 8);
    const bf16x8 qf1 = *reinterpret_cast<const bf16x8*>(qp + lm * HD + lg * 8 + 32);

    f32x4 cacc[4];
    #pragma unroll
    for (int vt = 0; vt < 4; ++vt) cacc[vt] = f32x4{0.f, 0.f, 0.f, 0.f};
    float m = -1e30f, l = 0.f;

    for (int k0 = kstart; k0 < kstart + KSPAN; k0 += 64) {
        // ---- S^T tiles: direct K loads (L2-resident) ----
        f32x4 accs[4];
        #pragma unroll
        for (int kt = 0; kt < 4; ++kt) {
            const short* kr = kp + (size_t)(k0 + kt * 16 + lm) * HD + lg * 8;
            const bf16x8 kf0 = *reinterpret_cast<const bf16x8*>(kr);
            const bf16x8 kf1 = *reinterpret_cast<const bf16x8*>(kr + 32);
            f32x4 z = f32x4{0.f, 0.f, 0.f, 0.f};
            z = __builtin_amdgcn_mfma_f32_16x16x32_bf16(kf0, qf0, z, 0, 0, 0);
            z = __builtin_amdgcn_mfma_f32_16x16x32_bf16(kf1, qf1, z, 0, 0, 0);
            accs[kt] = z;
        }

        // ---- online softmax in log2 units (per-lane q = lm) ----
        float p[4][4];
        float tmax = -3.0e38f;
        #pragma unroll
        for (int kt = 0; kt < 4; ++kt) {
            const f32x4 mv = *reinterpret_cast<const f32x4*>(&mk[k0 + kt * 16 + 4 * lg]);
            #pragma unroll
            for (int r = 0; r < 4; ++r) {
                p[kt][r] = accs[kt][r] + mv[r];
                tmax = fmaxf(tmax, p[kt][r]);
            }
        }
        tmax = fmaxf(tmax, __shfl_xor(tmax, 16));
        tmax = fmaxf(tmax, __shfl_xor(tmax, 32));
        const float mnew  = fmaxf(m, tmax);
        const float scale = exp2f(m - mnew);
        float psum = 0.f;
        #pragma unroll
        for (int kt = 0; kt < 4; ++kt)
            #pragma unroll
            for (int r = 0; r < 4; ++r) { p[kt][r] = exp2f(p[kt][r] - mnew); psum += p[kt][r]; }
        psum += __shfl_xor(psum, 16);
        psum += __shfl_xor(psum, 32);
        l = l * scale + psum;
        m = mnew;

        bf16x4 pa[4];
        #pragma unroll
        for (int kt = 0; kt < 4; ++kt) {
            bf16x4 tt;
            tt[0] = f2bf(p[kt][0]); tt[1] = f2bf(p[kt][1]);
            tt[2] = f2bf(p[kt][2]); tt[3] = f2bf(p[kt][3]);
            pa[kt] = tt;
        }
        #pragma unroll
        for (int r = 0; r < 4; ++r) {
            const float sr = __shfl(scale, lg * 4 + r);
            #pragma unroll
            for (int vt = 0; vt < 4; ++vt) cacc[vt][r] *= sr;
        }
        // ---- PV: V loaded inline per kt (small live set) ----
        #pragma unroll
        for (int kt = 0; kt < 4; ++kt) {
            #pragma unroll
            for (int vt = 0; vt < 4; ++vt) {
                const bf16x4 vf = *reinterpret_cast<const bf16x4*>(
                    vp + (size_t)(vt * 16 + lm) * N_ + k0 + kt * 16 + lg * 4);
                cacc[vt] = __builtin_amdgcn_mfma_f32_16x16x16bf16_1k(
                    pa[kt], vf, cacc[vt], 0, 0, 0);
            }
        }
    }

    float* ctxp = (s == 0) ? ctx0 : ctx1;
    #pragma unroll
    for (int r = 0; r < 4; ++r) {
        float* orow = ctxp + ((size_t)b * N_ + q0 + lg * 4 + r) * HID + h * HD;
        #pragma unroll
        for (int vt = 0; vt < 4; ++vt) orow[vt * 16 + lm] = cacc[vt][r];
    }
    if (lane < 16) {
        const size_t idx = (size_t)s * (B_ * NH * N_) + bh * N_ + q0 + lane;
        m_part[idx] = m;
        l_part[idx] = l;
    }
}

// ---------------------------------------------------------------------------
// K2b: merge NSPLIT=2 partials (log2-unit maxima).  grid 12288 x 256.
// ---------------------------------------------------------------------------
__global__ __launch_bounds__(256) void merge_kernel(
    float* __restrict__ ctx0, const float* __restrict__ ctx1,
    const float* __restrict__ m_part, const float* __restrict__ l_part,
    float* __restrict__ m_ws, float* __restrict__ l_ws)
{
    const int gid  = blockIdx.x * 256 + threadIdx.x;
    const int row  = gid >> 6;
    const int lane = gid & 63;
    const int bh = row >> 11;
    const int n  = row & 2047;
    const int b  = bh / NH, h = bh % NH;
    constexpr int PS = B_ * NH * N_;

    const float m0 = m_part[row], m1 = m_part[PS + row];
    const float l0 = l_part[row], l1 = l_part[PS + row];
    const float M  = fmaxf(m0, m1);
    const float w0 = exp2f(m0 - M), w1 = exp2f(m1 - M);
    const float L  = w0 * l0 + w1 * l1;
    const float invL = 1.f / L;

    const size_t cidx = ((size_t)b * N_ + n) * HID + h * HD + lane;
    ctx0[cidx] = (w0 * ctx0[cidx] + w1 * ctx1[cidx]) * invL;

    if (lane == 0) { m_ws[row] = M; l_ws[row] = L; }
}

// ---------------------------------------------------------------------------
// K3: attn_weights = sum_h probs / 12.  grid (N/16, N/256, B), block 256.
// ---------------------------------------------------------------------------
__global__ __launch_bounds__(256) void attnw_kernel(
    const short* __restrict__ qb, const short* __restrict__ kbm,
    const float* __restrict__ mks, const float* __restrict__ m_ws,
    const float* __restrict__ l_ws, float* __restrict__ out_attn)
{
    const int qt = blockIdx.x, ct = blockIdx.y, b = blockIdx.z;
    const int lane = threadIdx.x & 63;
    const int wave = threadIdx.x >> 6;
    const int lg = lane >> 4, lm = lane & 15;
    const int q0 = qt * 16;
    const int kbase = ct * 256 + wave * 64;

    float mv[4];
    #pragma unroll
    for (int kt = 0; kt < 4; ++kt) mv[kt] = mks[(size_t)b * N_ + kbase + kt * 16 + lm];

    f32x4 accw[4];
    #pragma unroll
    for (int kt = 0; kt < 4; ++kt) accw[kt] = f32x4{0.f, 0.f, 0.f, 0.f};

    for (int h = 0; h < NH; ++h) {
        const size_t bh = (size_t)(b * NH + h);
        const short* qp = qb + (bh * N_ + q0) * HD;
        const bf16x8 qf0 = *reinterpret_cast<const bf16x8*>(qp + lm * HD + lg * 8);
        const bf16x8 qf1 = *reinterpret_cast<const bf16x8*>(qp + lm * HD + lg * 8 + 32);
        const short* kp = kbm + bh * N_ * HD;
        float mr[4], il[4];
        #pragma unroll
        for (int r = 0; r < 4; ++r) {
            mr[r] = m_ws[bh * N_ + q0 + lg * 4 + r];
            il[r] = 1.f / l_ws[bh * N_ + q0 + lg * 4 + r];
        }
        #pragma unroll
        for (int kt = 0; kt < 4; ++kt) {
            const short* kr = kp + (size_t)(kbase + kt * 16 + lm) * HD + lg * 8;
            const bf16x8 kf0 = *reinterpret_cast<const bf16x8*>(kr);
            const bf16x8 kf1 = *reinterpret_cast<const bf16x8*>(kr + 32);
            f32x4 z = f32x4{0.f, 0.f, 0.f, 0.f};
            z = __builtin_amdgcn_mfma_f32_16x16x32_bf16(qf0, kf0, z, 0, 0, 0);
            z = __builtin_amdgcn_mfma_f32_16x16x32_bf16(qf1, kf1, z, 0, 0, 0);
            #pragma unroll
            for (int r = 0; r < 4; ++r)
                accw[kt][r] += exp2f(z[r] + mv[kt] - mr[r]) * il[r];
        }
    }
    #pragma unroll
    for (int kt = 0; kt < 4; ++kt)
        #pragma unroll
        for (int r = 0; r < 4; ++r)
            out_attn[((size_t)b * N_ + q0 + lg * 4 + r) * N_ + kbase + kt * 16 + lm]
                = accw[kt][r] * (1.0f / 12.0f);
}

// ---------------------------------------------------------------------------
extern "C" void kernel_launch(void* const* d_in, const int* in_sizes, int n_in,
                              void* d_out, int out_size, void* d_ws, size_t ws_size,
                              hipStream_t stream) {
    (void)in_sizes; (void)n_in; (void)out_size;
    const float* s1   = (const float*)d_in[0];
    const float* s2   = (const float*)d_in[1];
    const float* mask = (const float*)d_in[2];
    const float* Wq   = (const float*)d_in[3];
    const float* bq   = (const float*)d_in[4];
    const float* Wk   = (const float*)d_in[5];
    const float* bk   = (const float*)d_in[6];
    const float* Wv   = (const float*)d_in[7];
    const float* bv   = (const float*)d_in[8];

    float* out_ctx  = (float*)d_out;
    float* out_attn = out_ctx + (size_t)B_ * N_ * HID;

    const size_t xlen = (size_t)B_ * N_ * 1536;
    const size_t qkv  = (size_t)B_ * NH * N_ * HD;
    const size_t rows = (size_t)B_ * NH * N_;
    short* X1   = (short*)d_ws;
    short* X2   = X1 + xlen;
    short* WT   = X2 + xlen;
    short* qb   = WT + (size_t)3 * HID * HID;
    short* kbm  = qb + qkv;
    short* vtb  = kbm + qkv;
    float* ctx1 = (float*)(vtb + qkv);
    float* m_part = ctx1 + (size_t)B_ * N_ * HID;
    float* l_part = m_part + NSPLIT * rows;
    float* m_ws   = l_part + NSPLIT * rows;
    float* l_ws   = m_ws + rows;
    float* mks    = l_ws + rows;
    const size_t need = (size_t)((char*)(mks + (size_t)B_ * N_) - (char*)d_ws);
    if (ws_size < need) return;

    prep_x<<<6148, 256, 0, stream>>>(s1, s2, mask, X1, X2, mks);
    prep_w<<<dim3(12, 12, 3), 256, 0, stream>>>(Wq, Wk, Wv, WT);
    proj_mfma<<<dim3(32, 12, 3), 256, 0, stream>>>(X1, X2, WT, bq, bk, bv, qb, kbm, vtb);
    flash_kernel<<<dim3(N_ / 64, NH, B_ * NSPLIT), 256, 0, stream>>>(
        qb, kbm, vtb, mks, out_ctx, ctx1, m_part, l_part);
    merge_kernel<<<(B_ * N_ * HID) / 256, 256, 0, stream>>>(
        out_ctx, ctx1, m_part, l_part, m_ws, l_ws);
    attnw_kernel<<<dim3(N_ / 16, N_ / 256, B_), 256, 0, stream>>>(
        qb, kbm, mks, m_ws, l_ws, out_attn);
}

// Round 10
// 481.484 us; speedup vs baseline: 1.0790x; 1.0790x over previous
//
#include <hip/hip_runtime.h>
#include <stdint.h>

// Cross-attention forward: B=2, N1=N2=2048, HID=768, 12 heads x 64.
// Round 10: r9 with ONE fix — the inline-asm v_cvt_pk_bf16_f32 P-pack is
// replaced by software RNE f2bf. cvt_pk's rounding biased packed P low by
// ~2^-10 relative while l stayed fp32 -> systematic ctx bias ~2.5e-3
// (matched r8=2.48e-3 / r9=2.65e-3 with and without split proj).
// Keeps: split proj (KSTEPS=24), deferred-PV flash, exp2 units, attnw x2.

typedef __attribute__((ext_vector_type(8))) short bf16x8;
typedef __attribute__((ext_vector_type(4))) short bf16x4;
typedef __attribute__((ext_vector_type(4))) float f32x4;

constexpr int B_  = 2;
constexpr int N_  = 2048;   // N1 == N2
constexpr int HID = 768;
constexpr int NH  = 12;
constexpr int HD  = 64;
constexpr int RS  = 144;    // LDS row stride bytes: 128 data + 16 pad
constexpr int NSPLIT = 2;
constexpr int KSPAN  = N_ / NSPLIT;   // 1024
constexpr int NT     = KSPAN / 64;    // 16 tiles per flash block
constexpr float L2E = 1.4426950408889634f;   // log2(e)

__device__ __forceinline__ short f2bf(float f) {   // RNE float->bf16
    uint32_t u = __builtin_bit_cast(uint32_t, f);
    u = (u + 0x7fffu + ((u >> 16) & 1u)) >> 16;
    return (short)u;
}

// ---------------------------------------------------------------------------
// P0a: X -> (hi|lo) bf16 rows of 1536.  hi = trunc-bf16(x), lo = RNE(x-hi).
// Blocks >= 6144 prescale mask by log2e.
// ---------------------------------------------------------------------------
__global__ __launch_bounds__(256) void prep_x(
    const float* __restrict__ s1, const float* __restrict__ s2,
    const float* __restrict__ mask,
    short* __restrict__ X1, short* __restrict__ X2, float* __restrict__ mks)
{
    const int PT = (B_ * N_ * HID) / 4;       // 786432 quads per tensor
    if (blockIdx.x >= 6144) {
        const int idx = (blockIdx.x - 6144) * 256 + threadIdx.x;   // < 1024
        const float4 mv = *reinterpret_cast<const float4*>(&mask[idx * 4]);
        *reinterpret_cast<float4*>(&mks[idx * 4]) =
            make_float4(mv.x * L2E, mv.y * L2E, mv.z * L2E, mv.w * L2E);
        return;
    }
    int i = blockIdx.x * 256 + threadIdx.x;
    const float* S; short* X;
    if (i < PT) { S = s1; X = X1; } else { S = s2; X = X2; i -= PT; }
    const int e   = i * 4;
    const int row = e / HID;
    const int col = e - row * HID;
    const float4 v = *reinterpret_cast<const float4*>(&S[e]);
    float vs[4] = {v.x, v.y, v.z, v.w};
    short4 hi, lo;
    short* hp = &hi.x; short* lp = &lo.x;
    #pragma unroll
    for (int j = 0; j < 4; ++j) {
        const uint32_t u = __builtin_bit_cast(uint32_t, vs[j]);
        hp[j] = (short)(u >> 16);
        const float hif = __builtin_bit_cast(float, u & 0xffff0000u);
        lp[j] = f2bf(vs[j] - hif);
    }
    short* dst = X + (size_t)row * 1536 + col;
    *reinterpret_cast<short4*>(dst)       = hi;
    *reinterpret_cast<short4*>(dst + 768) = lo;
}

// ---------------------------------------------------------------------------
// P0b: W [k][n] fp32 -> WT [n][k] bf16 (3 matrices).  grid (12,12,3) x 256.
// ---------------------------------------------------------------------------
__global__ __launch_bounds__(256) void prep_w(
    const float* __restrict__ Wq, const float* __restrict__ Wk,
    const float* __restrict__ Wv, short* __restrict__ WT)
{
    const int z = blockIdx.z;
    const float* W = (z == 0) ? Wq : (z == 1) ? Wk : Wv;
    short* O = WT + (size_t)z * HID * HID;
    __shared__ short Tl[64][66];
    const int k0 = blockIdx.x * 64, n0 = blockIdx.y * 64;
    const int t = threadIdx.x;
    const int rr = t >> 4, cc = (t & 15) * 4;
    #pragma unroll
    for (int i = 0; i < 4; ++i) {
        const int row = i * 16 + rr;
        const float4 w = *reinterpret_cast<const float4*>(&W[(size_t)(k0 + row) * HID + n0 + cc]);
        Tl[cc + 0][row] = f2bf(w.x);
        Tl[cc + 1][row] = f2bf(w.y);
        Tl[cc + 2][row] = f2bf(w.z);
        Tl[cc + 3][row] = f2bf(w.w);
    }
    __syncthreads();
    #pragma unroll
    for (int i = 0; i < 4; ++i) {
        const int n = i * 16 + rr;
        short4 o;
        o.x = Tl[n][cc + 0]; o.y = Tl[n][cc + 1];
        o.z = Tl[n][cc + 2]; o.w = Tl[n][cc + 3];
        *reinterpret_cast<short4*>(&O[(size_t)(n0 + n) * HID + k0 + cc]) = o;
    }
}

// ---------------------------------------------------------------------------
// K1: proj GEMM (bf16 MFMA, hi/lo split).  grid (32, 12, 3), block 256.
// Tile 128x64, BK=64. Reg-staged dbuf padded LDS. q,k: KSTEPS=24 (hi then lo,
// W repeats via ks%12); v: 12 (hi only).
// which=0: q*(0.125*log2e) -> qb; 1: k -> kbm; 2: v -> vtb [bh][d][n].
// ---------------------------------------------------------------------------
__global__ __launch_bounds__(256) void proj_mfma(
    const short* __restrict__ X1, const short* __restrict__ X2,
    const short* __restrict__ WT,
    const float* __restrict__ bq, const float* __restrict__ bk,
    const float* __restrict__ bv,
    short* __restrict__ qb, short* __restrict__ kbm, short* __restrict__ vtb)
{
    const int which = blockIdx.z;
    const char* Xb = (const char*)((which == 0) ? X1 : X2);        // row 3072 B
    const char* Wb = (const char*)(WT + (size_t)which * HID * HID); // row 1536 B
    const float* bias = (which == 0) ? bq : (which == 1) ? bk : bv;
    const int m0 = blockIdx.x * 128;
    const int n0 = blockIdx.y * 64;
    const int t = threadIdx.x;
    const int lane = t & 63;
    const int lg = lane >> 4, lm = lane & 15;
    const int wave = t >> 6;
    const int wr = wave >> 1, wc = wave & 1;

    __shared__ __align__(16) char Al[2][128 * RS];
    __shared__ __align__(16) char Bl[2][64 * RS];

    const int KSTEPS = (which == 2) ? 12 : 24;

    f32x4 acc[4][2];
    #pragma unroll
    for (int mt = 0; mt < 4; ++mt)
        #pragma unroll
        for (int nt = 0; nt < 2; ++nt) acc[mt][nt] = f32x4{0.f, 0.f, 0.f, 0.f};

    int4 ra[4], rb[2];
    auto loadAB = [&](int ks) {
        const int ka = ks * 128;            // byte col into X row (hi then lo)
        const int kw = (ks % 12) * 128;     // byte col into WT row (W repeats)
        #pragma unroll
        for (int u = 0; u < 4; ++u) {
            const int c = u * 256 + t;      // row=c>>3, j=c&7
            ra[u] = *reinterpret_cast<const int4*>(
                Xb + (size_t)(m0 + (c >> 3)) * 3072 + ka + (c & 7) * 16);
        }
        #pragma unroll
        for (int u = 0; u < 2; ++u) {
            const int c = u * 256 + t;
            rb[u] = *reinterpret_cast<const int4*>(
                Wb + (size_t)(n0 + (c >> 3)) * 1536 + kw + (c & 7) * 16);
        }
    };
    auto storeAB = [&](int buf) {
        #pragma unroll
        for (int u = 0; u < 4; ++u) {
            const int c = u * 256 + t;      // byte = row*RS + j*16
            *reinterpret_cast<int4*>(&Al[buf][c * 16 + (c >> 3) * 16]) = ra[u];
        }
        #pragma unroll
        for (int u = 0; u < 2; ++u) {
            const int c = u * 256 + t;
            *reinterpret_cast<int4*>(&Bl[buf][c * 16 + (c >> 3) * 16]) = rb[u];
        }
    };

    loadAB(0);
    storeAB(0);
    __syncthreads();

    for (int ks = 0; ks < KSTEPS; ++ks) {
        const bool more = (ks + 1 < KSTEPS);
        if (more) loadAB(ks + 1);
        const char* Ab = Al[ks & 1];
        const char* Bb = Bl[ks & 1];
        #pragma unroll
        for (int ksub = 0; ksub < 2; ++ksub) {
            const int jj = ksub * 4 + lg;
            bf16x8 a[4], bb[2];
            #pragma unroll
            for (int mt = 0; mt < 4; ++mt) {
                const int r = wr * 64 + mt * 16 + lm;
                a[mt] = *reinterpret_cast<const bf16x8*>(Ab + r * RS + jj * 16);
            }
            #pragma unroll
            for (int nt = 0; nt < 2; ++nt) {
                const int r = wc * 32 + nt * 16 + lm;
                bb[nt] = *reinterpret_cast<const bf16x8*>(Bb + r * RS + jj * 16);
            }
            __builtin_amdgcn_s_setprio(1);
            #pragma unroll
            for (int mt = 0; mt < 4; ++mt)
                #pragma unroll
                for (int nt = 0; nt < 2; ++nt)
                    acc[mt][nt] = __builtin_amdgcn_mfma_f32_16x16x32_bf16(
                        a[mt], bb[nt], acc[mt][nt], 0, 0, 0);
            __builtin_amdgcn_s_setprio(0);
        }
        if (more) storeAB((ks + 1) & 1);
        __syncthreads();
    }

    const int b = m0 >> 11;
    const int head = blockIdx.y;
    const size_t bh = (size_t)(b * NH + head);

    if (which != 2) {
        const float sc = (which == 0) ? (0.125f * L2E) : 1.0f;
        short* dst = (which == 0) ? qb : kbm;
        #pragma unroll
        for (int mt = 0; mt < 4; ++mt)
            #pragma unroll
            for (int nt = 0; nt < 2; ++nt) {
                const int dd = wc * 32 + nt * 16 + lm;
                const float bi = bias[n0 + dd];
                #pragma unroll
                for (int r = 0; r < 4; ++r) {
                    const int m = m0 + wr * 64 + mt * 16 + 4 * lg + r;
                    const int n = m & 2047;
                    dst[(bh * N_ + n) * HD + dd] = f2bf((acc[mt][nt][r] + bi) * sc);
                }
            }
    } else {
        short* Ct = (short*)Al[0];           // [64 d][128 m] bf16
        #pragma unroll
        for (int mt = 0; mt < 4; ++mt)
            #pragma unroll
            for (int nt = 0; nt < 2; ++nt) {
                const int dd = wc * 32 + nt * 16 + lm;
                const float bi = bias[n0 + dd];
                #pragma unroll
                for (int r = 0; r < 4; ++r) {
                    const int ml = wr * 64 + mt * 16 + 4 * lg + r;
                    Ct[dd * 128 + ml] = f2bf(acc[mt][nt][r] + bi);
                }
            }
        __syncthreads();
        const int d = t >> 2, seg = t & 3;
        const short* src = Ct + d * 128 + seg * 32;
        short* dv = vtb + (bh * HD + d) * N_ + (m0 & 2047) + seg * 32;
        #pragma unroll
        for (int u = 0; u < 4; ++u)
            *reinterpret_cast<int4*>(dv + u * 8) = *reinterpret_cast<const int4*>(src + u * 8);
    }
}

// ---------------------------------------------------------------------------
// K2: split-K flash, deferred-PV pipeline.  grid (N/64, NH, B*NSPLIT).
// Iter t: [V(t-1)+mask(t) loads | K(t+1) loads] -> QK(t) MFMA ->
// [rescale cacc + PV(t-1) MFMA] -> softmax(t) -> f2bf pack -> storeK.
// ---------------------------------------------------------------------------
__global__ __launch_bounds__(256) void flash_kernel(
    const short* __restrict__ qb, const short* __restrict__ kbm,
    const short* __restrict__ vtb, const float* __restrict__ mks,
    float* __restrict__ ctx0, float* __restrict__ ctx1,
    float* __restrict__ m_part, float* __restrict__ l_part)
{
    const int qt = blockIdx.x, h = blockIdx.y;
    const int b = blockIdx.z / NSPLIT, s = blockIdx.z % NSPLIT;
    const int t = threadIdx.x;
    const int lane = t & 63;
    const int wave = __builtin_amdgcn_readfirstlane(t >> 6);
    const int lg = lane >> 4, lm = lane & 15;
    const int q0 = qt * 64 + wave * 16;
    const int kstart = s * KSPAN;

    __shared__ __align__(16) char Kl[2][64 * RS];

    const size_t bh = (size_t)(b * NH + h);
    const short* qp  = qb  + (bh * N_ + q0) * HD;
    const char*  kpb = (const char*)(kbm + bh * N_ * HD);   // row 128 B
    const short* vp  = vtb + bh * HD * N_;
    const float* mk  = mks + (size_t)b * N_;

    const bf16x8 qf0 = *reinterpret_cast<const bf16x8*>(qp + lm * HD + lg * 8);
    const bf16x8 qf1 = *reinterpret_cast<const bf16x8*>(qp + lm * HD + lg * 8 + 32);

    f32x4 cacc[4];
    #pragma unroll
    for (int vt = 0; vt < 4; ++vt) cacc[vt] = f32x4{0.f, 0.f, 0.f, 0.f};
    float m = -1e30f, l = 0.f;
    float scale_prev = 1.f;
    bf16x4 pa_prev[4];

    int4 rk[2];
    auto loadK = [&](int krow) {
        #pragma unroll
        for (int u = 0; u < 2; ++u) {
            const int c = u * 256 + t;
            rk[u] = *reinterpret_cast<const int4*>(
                kpb + (size_t)(krow + (c >> 3)) * 128 + (c & 7) * 16);
        }
    };
    auto storeK = [&](int buf) {
        #pragma unroll
        for (int u = 0; u < 2; ++u) {
            const int c = u * 256 + t;
            *reinterpret_cast<int4*>(&Kl[buf][c * 16 + (c >> 3) * 16]) = rk[u];
        }
    };

    loadK(kstart);
    storeK(0);
    __syncthreads();

    for (int it = 0; it < NT; ++it) {
        const int k0  = kstart + it * 64;
        const int cur = it & 1;
        const bool more = (it + 1 < NT);

        // a) V loads for the DEFERRED tile (t-1) + mask for tile t
        bf16x4 vf[4][4];
        if (it > 0) {
            #pragma unroll
            for (int kt = 0; kt < 4; ++kt)
                #pragma unroll
                for (int vt = 0; vt < 4; ++vt)
                    vf[kt][vt] = *reinterpret_cast<const bf16x4*>(
                        vp + (size_t)(vt * 16 + lm) * N_ + (k0 - 64) + kt * 16 + lg * 4);
        }
        f32x4 mv4[4];
        #pragma unroll
        for (int kt = 0; kt < 4; ++kt)
            mv4[kt] = *reinterpret_cast<const f32x4*>(&mk[k0 + kt * 16 + 4 * lg]);

        // b) next K tile -> regs
        if (more) loadK(k0 + 64);

        // c) QK(t) from LDS
        const char* Kb = Kl[cur];
        f32x4 accs[4];
        __builtin_amdgcn_s_setprio(1);
        #pragma unroll
        for (int kt = 0; kt < 4; ++kt) {
            const int r = kt * 16 + lm;
            const bf16x8 kf0 = *reinterpret_cast<const bf16x8*>(Kb + r * RS + lg * 16);
            const bf16x8 kf1 = *reinterpret_cast<const bf16x8*>(Kb + r * RS + (lg + 4) * 16);
            f32x4 z = f32x4{0.f, 0.f, 0.f, 0.f};
            z = __builtin_amdgcn_mfma_f32_16x16x32_bf16(kf0, qf0, z, 0, 0, 0);
            z = __builtin_amdgcn_mfma_f32_16x16x32_bf16(kf1, qf1, z, 0, 0, 0);
            accs[kt] = z;
        }
        __builtin_amdgcn_s_setprio(0);

        // d) deferred: rescale cacc + PV(t-1)  (overlaps QK(t) result latency)
        if (it > 0) {
            #pragma unroll
            for (int r = 0; r < 4; ++r) {
                const float sr = __shfl(scale_prev, lg * 4 + r);
                #pragma unroll
                for (int vt = 0; vt < 4; ++vt) cacc[vt][r] *= sr;
            }
            __builtin_amdgcn_s_setprio(1);
            #pragma unroll
            for (int kt = 0; kt < 4; ++kt)
                #pragma unroll
                for (int vt = 0; vt < 4; ++vt)
                    cacc[vt] = __builtin_amdgcn_mfma_f32_16x16x16bf16_1k(
                        pa_prev[kt], vf[kt][vt], cacc[vt], 0, 0, 0);
            __builtin_amdgcn_s_setprio(0);
        }

        // e) softmax(t) in log2 units (per-lane q = lm)
        float p[4][4];
        float tmax = -3.0e38f;
        #pragma unroll
        for (int kt = 0; kt < 4; ++kt)
            #pragma unroll
            for (int r = 0; r < 4; ++r) {
                p[kt][r] = accs[kt][r] + mv4[kt][r];
                tmax = fmaxf(tmax, p[kt][r]);
            }
        tmax = fmaxf(tmax, __shfl_xor(tmax, 16));
        tmax = fmaxf(tmax, __shfl_xor(tmax, 32));
        const float mnew  = fmaxf(m, tmax);
        const float sc_t  = exp2f(m - mnew);
        float psum = 0.f;
        #pragma unroll
        for (int kt = 0; kt < 4; ++kt)
            #pragma unroll
            for (int r = 0; r < 4; ++r) { p[kt][r] = exp2f(p[kt][r] - mnew); psum += p[kt][r]; }
        psum += __shfl_xor(psum, 16);
        psum += __shfl_xor(psum, 32);
        l = l * sc_t + psum;
        m = mnew;

        // f) pack P(t) -> pa_prev with software RNE (unbiased; cvt_pk was not)
        #pragma unroll
        for (int kt = 0; kt < 4; ++kt) {
            bf16x4 tt;
            tt[0] = f2bf(p[kt][0]); tt[1] = f2bf(p[kt][1]);
            tt[2] = f2bf(p[kt][2]); tt[3] = f2bf(p[kt][3]);
            pa_prev[kt] = tt;
        }
        scale_prev = sc_t;

        // g) stage next K into other buffer, h) barrier
        if (more) storeK(cur ^ 1);
        __syncthreads();
    }

    // epilogue: finish the last deferred tile
    {
        const int k0 = kstart + (NT - 1) * 64;
        bf16x4 vf[4][4];
        #pragma unroll
        for (int kt = 0; kt < 4; ++kt)
            #pragma unroll
            for (int vt = 0; vt < 4; ++vt)
                vf[kt][vt] = *reinterpret_cast<const bf16x4*>(
                    vp + (size_t)(vt * 16 + lm) * N_ + k0 + kt * 16 + lg * 4);
        #pragma unroll
        for (int r = 0; r < 4; ++r) {
            const float sr = __shfl(scale_prev, lg * 4 + r);
            #pragma unroll
            for (int vt = 0; vt < 4; ++vt) cacc[vt][r] *= sr;
        }
        #pragma unroll
        for (int kt = 0; kt < 4; ++kt)
            #pragma unroll
            for (int vt = 0; vt < 4; ++vt)
                cacc[vt] = __builtin_amdgcn_mfma_f32_16x16x16bf16_1k(
                    pa_prev[kt], vf[kt][vt], cacc[vt], 0, 0, 0);
    }

    float* ctxp = (s == 0) ? ctx0 : ctx1;
    #pragma unroll
    for (int r = 0; r < 4; ++r) {
        float* orow = ctxp + ((size_t)b * N_ + q0 + lg * 4 + r) * HID + h * HD;
        #pragma unroll
        for (int vt = 0; vt < 4; ++vt) orow[vt * 16 + lm] = cacc[vt][r];
    }
    if (lane < 16) {
        const size_t idx = (size_t)s * (B_ * NH * N_) + bh * N_ + q0 + lane;
        m_part[idx] = m;
        l_part[idx] = l;
    }
}

// ---------------------------------------------------------------------------
// K2b: merge NSPLIT=2 partials (log2-unit maxima).  grid 12288 x 256.
// ---------------------------------------------------------------------------
__global__ __launch_bounds__(256) void merge_kernel(
    float* __restrict__ ctx0, const float* __restrict__ ctx1,
    const float* __restrict__ m_part, const float* __restrict__ l_part,
    float* __restrict__ m_ws, float* __restrict__ l_ws)
{
    const int gid  = blockIdx.x * 256 + threadIdx.x;
    const int row  = gid >> 6;
    const int lane = gid & 63;
    const int bh = row >> 11;
    const int n  = row & 2047;
    const int b  = bh / NH, h = bh % NH;
    constexpr int PS = B_ * NH * N_;

    const float m0 = m_part[row], m1 = m_part[PS + row];
    const float l0 = l_part[row], l1 = l_part[PS + row];
    const float M  = fmaxf(m0, m1);
    const float w0 = exp2f(m0 - M), w1 = exp2f(m1 - M);
    const float L  = w0 * l0 + w1 * l1;
    const float invL = 1.f / L;

    const size_t cidx = ((size_t)b * N_ + n) * HID + h * HD + lane;
    ctx0[cidx] = (w0 * ctx0[cidx] + w1 * ctx1[cidx]) * invL;

    if (lane == 0) { m_ws[row] = M; l_ws[row] = L; }
}

// ---------------------------------------------------------------------------
// K3: attn_weights = sum_h probs / 12.  grid (N/16, N/256, B), block 256.
// Heads unrolled x2: two independent load->MFMA->exp chains in flight.
// ---------------------------------------------------------------------------
__global__ __launch_bounds__(256) void attnw_kernel(
    const short* __restrict__ qb, const short* __restrict__ kbm,
    const float* __restrict__ mks, const float* __restrict__ m_ws,
    const float* __restrict__ l_ws, float* __restrict__ out_attn)
{
    const int qt = blockIdx.x, ct = blockIdx.y, b = blockIdx.z;
    const int lane = threadIdx.x & 63;
    const int wave = threadIdx.x >> 6;
    const int lg = lane >> 4, lm = lane & 15;
    const int q0 = qt * 16;
    const int kbase = ct * 256 + wave * 64;

    float mv[4];
    #pragma unroll
    for (int kt = 0; kt < 4; ++kt) mv[kt] = mks[(size_t)b * N_ + kbase + kt * 16 + lm];

    f32x4 accw[4];
    #pragma unroll
    for (int kt = 0; kt < 4; ++kt) accw[kt] = f32x4{0.f, 0.f, 0.f, 0.f};

    #pragma unroll 2
    for (int h = 0; h < NH; ++h) {
        const size_t bh = (size_t)(b * NH + h);
        const short* qp = qb + (bh * N_ + q0) * HD;
        const bf16x8 qf0 = *reinterpret_cast<const bf16x8*>(qp + lm * HD + lg * 8);
        const bf16x8 qf1 = *reinterpret_cast<const bf16x8*>(qp + lm * HD + lg * 8 + 32);
        const short* kp = kbm + bh * N_ * HD;
        float mr[4], il[4];
        #pragma unroll
        for (int r = 0; r < 4; ++r) {
            mr[r] = m_ws[bh * N_ + q0 + lg * 4 + r];
            il[r] = 1.f / l_ws[bh * N_ + q0 + lg * 4 + r];
        }
        #pragma unroll
        for (int kt = 0; kt < 4; ++kt) {
            const short* kr = kp + (size_t)(kbase + kt * 16 + lm) * HD + lg * 8;
            const bf16x8 kf0 = *reinterpret_cast<const bf16x8*>(kr);
            const bf16x8 kf1 = *reinterpret_cast<const bf16x8*>(kr + 32);
            f32x4 z = f32x4{0.f, 0.f, 0.f, 0.f};
            z = __builtin_amdgcn_mfma_f32_16x16x32_bf16(qf0, kf0, z, 0, 0, 0);
            z = __builtin_amdgcn_mfma_f32_16x16x32_bf16(qf1, kf1, z, 0, 0, 0);
            #pragma unroll
            for (int r = 0; r < 4; ++r)
                accw[kt][r] += exp2f(z[r] + mv[kt] - mr[r]) * il[r];
        }
    }
    #pragma unroll
    for (int kt = 0; kt < 4; ++kt)
        #pragma unroll
        for (int r = 0; r < 4; ++r)
            out_attn[((size_t)b * N_ + q0 + lg * 4 + r) * N_ + kbase + kt * 16 + lm]
                = accw[kt][r] * (1.0f / 12.0f);
}

// ---------------------------------------------------------------------------
extern "C" void kernel_launch(void* const* d_in, const int* in_sizes, int n_in,
                              void* d_out, int out_size, void* d_ws, size_t ws_size,
                              hipStream_t stream) {
    (void)in_sizes; (void)n_in; (void)out_size;
    const float* s1   = (const float*)d_in[0];
    const float* s2   = (const float*)d_in[1];
    const float* mask = (const float*)d_in[2];
    const float* Wq   = (const float*)d_in[3];
    const float* bq   = (const float*)d_in[4];
    const float* Wk   = (const float*)d_in[5];
    const float* bk   = (const float*)d_in[6];
    const float* Wv   = (const float*)d_in[7];
    const float* bv   = (const float*)d_in[8];

    float* out_ctx  = (float*)d_out;
    float* out_attn = out_ctx + (size_t)B_ * N_ * HID;

    const size_t xlen = (size_t)B_ * N_ * 1536;     // hi|lo shorts per tensor
    const size_t qkv  = (size_t)B_ * NH * N_ * HD;
    const size_t rows = (size_t)B_ * NH * N_;
    short* X1   = (short*)d_ws;
    short* X2   = X1 + xlen;
    short* WT   = X2 + xlen;
    short* qb   = WT + (size_t)3 * HID * HID;
    short* kbm  = qb + qkv;
    short* vtb  = kbm + qkv;
    float* ctx1 = (float*)(vtb + qkv);
    float* m_part = ctx1 + (size_t)B_ * N_ * HID;
    float* l_part = m_part + NSPLIT * rows;
    float* m_ws   = l_part + NSPLIT * rows;
    float* l_ws   = m_ws + rows;
    float* mks    = l_ws + rows;
    const size_t need = (size_t)((char*)(mks + (size_t)B_ * N_) - (char*)d_ws);
    if (ws_size < need) return;

    prep_x<<<6148, 256, 0, stream>>>(s1, s2, mask, X1, X2, mks);
    prep_w<<<dim3(12, 12, 3), 256, 0, stream>>>(Wq, Wk, Wv, WT);
    proj_mfma<<<dim3(32, 12, 3), 256, 0, stream>>>(X1, X2, WT, bq, bk, bv, qb, kbm, vtb);
    flash_kernel<<<dim3(N_ / 64, NH, B_ * NSPLIT), 256, 0, stream>>>(
        qb, kbm, vtb, mks, out_ctx, ctx1, m_part, l_part);
    merge_kernel<<<(B_ * N_ * HID) / 256, 256, 0, stream>>>(
        out_ctx, ctx1, m_part, l_part, m_ws, l_ws);
    attnw_kernel<<<dim3(N_ / 16, N_ / 256, B_), 256, 0, stream>>>(
        qb, kbm, mks, m_ws, l_ws, out_attn);
}

// Round 11
// 364.437 us; speedup vs baseline: 1.4255x; 1.3212x over previous
//
#include <hip/hip_runtime.h>
#include <stdint.h>

// Cross-attention forward: B=2, N1=N2=2048, HID=768, 12 heads x 64.
// Round 11: r10 + ONE change — V^T tile staged in LDS (block-cooperative
// coalesced loads, double-buffered) replacing per-wave scattered 8B V loads
// (16 instrs x 16 cache lines x 4 redundant waves per tile -> 2 instrs x 8
// lines per block). PV B-frags now ds_read_b64 from padded LDS.

typedef __attribute__((ext_vector_type(8))) short bf16x8;
typedef __attribute__((ext_vector_type(4))) short bf16x4;
typedef __attribute__((ext_vector_type(4))) float f32x4;

constexpr int B_  = 2;
constexpr int N_  = 2048;   // N1 == N2
constexpr int HID = 768;
constexpr int NH  = 12;
constexpr int HD  = 64;
constexpr int RS  = 144;    // LDS row stride bytes: 128 data + 16 pad
constexpr int NSPLIT = 2;
constexpr int KSPAN  = N_ / NSPLIT;   // 1024
constexpr int NT     = KSPAN / 64;    // 16 tiles per flash block
constexpr float L2E = 1.4426950408889634f;   // log2(e)

__device__ __forceinline__ short f2bf(float f) {   // RNE float->bf16
    uint32_t u = __builtin_bit_cast(uint32_t, f);
    u = (u + 0x7fffu + ((u >> 16) & 1u)) >> 16;
    return (short)u;
}

// ---------------------------------------------------------------------------
// P0a: X -> (hi|lo) bf16 rows of 1536.  hi = trunc-bf16(x), lo = RNE(x-hi).
// Blocks >= 6144 prescale mask by log2e.
// ---------------------------------------------------------------------------
__global__ __launch_bounds__(256) void prep_x(
    const float* __restrict__ s1, const float* __restrict__ s2,
    const float* __restrict__ mask,
    short* __restrict__ X1, short* __restrict__ X2, float* __restrict__ mks)
{
    const int PT = (B_ * N_ * HID) / 4;       // 786432 quads per tensor
    if (blockIdx.x >= 6144) {
        const int idx = (blockIdx.x - 6144) * 256 + threadIdx.x;   // < 1024
        const float4 mv = *reinterpret_cast<const float4*>(&mask[idx * 4]);
        *reinterpret_cast<float4*>(&mks[idx * 4]) =
            make_float4(mv.x * L2E, mv.y * L2E, mv.z * L2E, mv.w * L2E);
        return;
    }
    int i = blockIdx.x * 256 + threadIdx.x;
    const float* S; short* X;
    if (i < PT) { S = s1; X = X1; } else { S = s2; X = X2; i -= PT; }
    const int e   = i * 4;
    const int row = e / HID;
    const int col = e - row * HID;
    const float4 v = *reinterpret_cast<const float4*>(&S[e]);
    float vs[4] = {v.x, v.y, v.z, v.w};
    short4 hi, lo;
    short* hp = &hi.x; short* lp = &lo.x;
    #pragma unroll
    for (int j = 0; j < 4; ++j) {
        const uint32_t u = __builtin_bit_cast(uint32_t, vs[j]);
        hp[j] = (short)(u >> 16);
        const float hif = __builtin_bit_cast(float, u & 0xffff0000u);
        lp[j] = f2bf(vs[j] - hif);
    }
    short* dst = X + (size_t)row * 1536 + col;
    *reinterpret_cast<short4*>(dst)       = hi;
    *reinterpret_cast<short4*>(dst + 768) = lo;
}

// ---------------------------------------------------------------------------
// P0b: W [k][n] fp32 -> WT [n][k] bf16 (3 matrices).  grid (12,12,3) x 256.
// ---------------------------------------------------------------------------
__global__ __launch_bounds__(256) void prep_w(
    const float* __restrict__ Wq, const float* __restrict__ Wk,
    const float* __restrict__ Wv, short* __restrict__ WT)
{
    const int z = blockIdx.z;
    const float* W = (z == 0) ? Wq : (z == 1) ? Wk : Wv;
    short* O = WT + (size_t)z * HID * HID;
    __shared__ short Tl[64][66];
    const int k0 = blockIdx.x * 64, n0 = blockIdx.y * 64;
    const int t = threadIdx.x;
    const int rr = t >> 4, cc = (t & 15) * 4;
    #pragma unroll
    for (int i = 0; i < 4; ++i) {
        const int row = i * 16 + rr;
        const float4 w = *reinterpret_cast<const float4*>(&W[(size_t)(k0 + row) * HID + n0 + cc]);
        Tl[cc + 0][row] = f2bf(w.x);
        Tl[cc + 1][row] = f2bf(w.y);
        Tl[cc + 2][row] = f2bf(w.z);
        Tl[cc + 3][row] = f2bf(w.w);
    }
    __syncthreads();
    #pragma unroll
    for (int i = 0; i < 4; ++i) {
        const int n = i * 16 + rr;
        short4 o;
        o.x = Tl[n][cc + 0]; o.y = Tl[n][cc + 1];
        o.z = Tl[n][cc + 2]; o.w = Tl[n][cc + 3];
        *reinterpret_cast<short4*>(&O[(size_t)(n0 + n) * HID + k0 + cc]) = o;
    }
}

// ---------------------------------------------------------------------------
// K1: proj GEMM (bf16 MFMA, hi/lo split).  grid (32, 12, 3), block 256.
// Tile 128x64, BK=64. Reg-staged dbuf padded LDS. q,k: KSTEPS=24 (hi then lo,
// W repeats via ks%12); v: 12 (hi only).
// which=0: q*(0.125*log2e) -> qb; 1: k -> kbm; 2: v -> vtb [bh][d][n].
// ---------------------------------------------------------------------------
__global__ __launch_bounds__(256) void proj_mfma(
    const short* __restrict__ X1, const short* __restrict__ X2,
    const short* __restrict__ WT,
    const float* __restrict__ bq, const float* __restrict__ bk,
    const float* __restrict__ bv,
    short* __restrict__ qb, short* __restrict__ kbm, short* __restrict__ vtb)
{
    const int which = blockIdx.z;
    const char* Xb = (const char*)((which == 0) ? X1 : X2);        // row 3072 B
    const char* Wb = (const char*)(WT + (size_t)which * HID * HID); // row 1536 B
    const float* bias = (which == 0) ? bq : (which == 1) ? bk : bv;
    const int m0 = blockIdx.x * 128;
    const int n0 = blockIdx.y * 64;
    const int t = threadIdx.x;
    const int lane = t & 63;
    const int lg = lane >> 4, lm = lane & 15;
    const int wave = t >> 6;
    const int wr = wave >> 1, wc = wave & 1;

    __shared__ __align__(16) char Al[2][128 * RS];
    __shared__ __align__(16) char Bl[2][64 * RS];

    const int KSTEPS = (which == 2) ? 12 : 24;

    f32x4 acc[4][2];
    #pragma unroll
    for (int mt = 0; mt < 4; ++mt)
        #pragma unroll
        for (int nt = 0; nt < 2; ++nt) acc[mt][nt] = f32x4{0.f, 0.f, 0.f, 0.f};

    int4 ra[4], rb[2];
    auto loadAB = [&](int ks) {
        const int ka = ks * 128;            // byte col into X row (hi then lo)
        const int kw = (ks % 12) * 128;     // byte col into WT row (W repeats)
        #pragma unroll
        for (int u = 0; u < 4; ++u) {
            const int c = u * 256 + t;      // row=c>>3, j=c&7
            ra[u] = *reinterpret_cast<const int4*>(
                Xb + (size_t)(m0 + (c >> 3)) * 3072 + ka + (c & 7) * 16);
        }
        #pragma unroll
        for (int u = 0; u < 2; ++u) {
            const int c = u * 256 + t;
            rb[u] = *reinterpret_cast<const int4*>(
                Wb + (size_t)(n0 + (c >> 3)) * 1536 + kw + (c & 7) * 16);
        }
    };
    auto storeAB = [&](int buf) {
        #pragma unroll
        for (int u = 0; u < 4; ++u) {
            const int c = u * 256 + t;      // byte = row*RS + j*16
            *reinterpret_cast<int4*>(&Al[buf][c * 16 + (c >> 3) * 16]) = ra[u];
        }
        #pragma unroll
        for (int u = 0; u < 2; ++u) {
            const int c = u * 256 + t;
            *reinterpret_cast<int4*>(&Bl[buf][c * 16 + (c >> 3) * 16]) = rb[u];
        }
    };

    loadAB(0);
    storeAB(0);
    __syncthreads();

    for (int ks = 0; ks < KSTEPS; ++ks) {
        const bool more = (ks + 1 < KSTEPS);
        if (more) loadAB(ks + 1);
        const char* Ab = Al[ks & 1];
        const char* Bb = Bl[ks & 1];
        #pragma unroll
        for (int ksub = 0; ksub < 2; ++ksub) {
            const int jj = ksub * 4 + lg;
            bf16x8 a[4], bb[2];
            #pragma unroll
            for (int mt = 0; mt < 4; ++mt) {
                const int r = wr * 64 + mt * 16 + lm;
                a[mt] = *reinterpret_cast<const bf16x8*>(Ab + r * RS + jj * 16);
            }
            #pragma unroll
            for (int nt = 0; nt < 2; ++nt) {
                const int r = wc * 32 + nt * 16 + lm;
                bb[nt] = *reinterpret_cast<const bf16x8*>(Bb + r * RS + jj * 16);
            }
            __builtin_amdgcn_s_setprio(1);
            #pragma unroll
            for (int mt = 0; mt < 4; ++mt)
                #pragma unroll
                for (int nt = 0; nt < 2; ++nt)
                    acc[mt][nt] = __builtin_amdgcn_mfma_f32_16x16x32_bf16(
                        a[mt], bb[nt], acc[mt][nt], 0, 0, 0);
            __builtin_amdgcn_s_setprio(0);
        }
        if (more) storeAB((ks + 1) & 1);
        __syncthreads();
    }

    const int b = m0 >> 11;
    const int head = blockIdx.y;
    const size_t bh = (size_t)(b * NH + head);

    if (which != 2) {
        const float sc = (which == 0) ? (0.125f * L2E) : 1.0f;
        short* dst = (which == 0) ? qb : kbm;
        #pragma unroll
        for (int mt = 0; mt < 4; ++mt)
            #pragma unroll
            for (int nt = 0; nt < 2; ++nt) {
                const int dd = wc * 32 + nt * 16 + lm;
                const float bi = bias[n0 + dd];
                #pragma unroll
                for (int r = 0; r < 4; ++r) {
                    const int m = m0 + wr * 64 + mt * 16 + 4 * lg + r;
                    const int n = m & 2047;
                    dst[(bh * N_ + n) * HD + dd] = f2bf((acc[mt][nt][r] + bi) * sc);
                }
            }
    } else {
        short* Ct = (short*)Al[0];           // [64 d][128 m] bf16
        #pragma unroll
        for (int mt = 0; mt < 4; ++mt)
            #pragma unroll
            for (int nt = 0; nt < 2; ++nt) {
                const int dd = wc * 32 + nt * 16 + lm;
                const float bi = bias[n0 + dd];
                #pragma unroll
                for (int r = 0; r < 4; ++r) {
                    const int ml = wr * 64 + mt * 16 + 4 * lg + r;
                    Ct[dd * 128 + ml] = f2bf(acc[mt][nt][r] + bi);
                }
            }
        __syncthreads();
        const int d = t >> 2, seg = t & 3;
        const short* src = Ct + d * 128 + seg * 32;
        short* dv = vtb + (bh * HD + d) * N_ + (m0 & 2047) + seg * 32;
        #pragma unroll
        for (int u = 0; u < 4; ++u)
            *reinterpret_cast<int4*>(dv + u * 8) = *reinterpret_cast<const int4*>(src + u * 8);
    }
}

// ---------------------------------------------------------------------------
// K2: split-K flash, deferred-PV + LDS-staged K and V^T.
// grid (N/64, NH, B*NSPLIT), block 256 (4 waves).
// Iter t: mask(t) loads | K(t+1),V(t) global->reg -> QK(t) from Kl[cur] ->
// [rescale + PV(t-1) from Vl[(t-1)&1]] -> softmax(t) -> f2bf pack ->
// storeK(cur^1), storeV(t&1) -> barrier.
// ---------------------------------------------------------------------------
__global__ __launch_bounds__(256) void flash_kernel(
    const short* __restrict__ qb, const short* __restrict__ kbm,
    const short* __restrict__ vtb, const float* __restrict__ mks,
    float* __restrict__ ctx0, float* __restrict__ ctx1,
    float* __restrict__ m_part, float* __restrict__ l_part)
{
    const int qt = blockIdx.x, h = blockIdx.y;
    const int b = blockIdx.z / NSPLIT, s = blockIdx.z % NSPLIT;
    const int t = threadIdx.x;
    const int lane = t & 63;
    const int wave = __builtin_amdgcn_readfirstlane(t >> 6);
    const int lg = lane >> 4, lm = lane & 15;
    const int q0 = qt * 64 + wave * 16;
    const int kstart = s * KSPAN;

    __shared__ __align__(16) char Kl[2][64 * RS];   // K rows (keys) x 128B
    __shared__ __align__(16) char Vl[2][64 * RS];   // V^T rows (d)   x 128B

    const size_t bh = (size_t)(b * NH + h);
    const short* qp  = qb  + (bh * N_ + q0) * HD;
    const char*  kpb = (const char*)(kbm + bh * N_ * HD);   // row 128 B
    const char*  vpb = (const char*)(vtb + bh * HD * N_);   // row N_*2 B
    const float* mk  = mks + (size_t)b * N_;

    const bf16x8 qf0 = *reinterpret_cast<const bf16x8*>(qp + lm * HD + lg * 8);
    const bf16x8 qf1 = *reinterpret_cast<const bf16x8*>(qp + lm * HD + lg * 8 + 32);

    f32x4 cacc[4];
    #pragma unroll
    for (int vt = 0; vt < 4; ++vt) cacc[vt] = f32x4{0.f, 0.f, 0.f, 0.f};
    float m = -1e30f, l = 0.f;
    float scale_prev = 1.f;
    bf16x4 pa_prev[4];

    int4 rk[2], rv[2];
    auto loadK = [&](int krow) {
        #pragma unroll
        for (int u = 0; u < 2; ++u) {
            const int c = u * 256 + t;
            rk[u] = *reinterpret_cast<const int4*>(
                kpb + (size_t)(krow + (c >> 3)) * 128 + (c & 7) * 16);
        }
    };
    auto storeK = [&](int buf) {
        #pragma unroll
        for (int u = 0; u < 2; ++u) {
            const int c = u * 256 + t;
            *reinterpret_cast<int4*>(&Kl[buf][c * 16 + (c >> 3) * 16]) = rk[u];
        }
    };
    auto loadV = [&](int k0) {   // V^T rows d = c>>3 (0..63), 64 keys from k0
        #pragma unroll
        for (int u = 0; u < 2; ++u) {
            const int c = u * 256 + t;
            rv[u] = *reinterpret_cast<const int4*>(
                vpb + (size_t)(c >> 3) * (N_ * 2) + (size_t)k0 * 2 + (c & 7) * 16);
        }
    };
    auto storeV = [&](int buf) {
        #pragma unroll
        for (int u = 0; u < 2; ++u) {
            const int c = u * 256 + t;
            *reinterpret_cast<int4*>(&Vl[buf][c * 16 + (c >> 3) * 16]) = rv[u];
        }
    };

    loadK(kstart);
    storeK(0);
    __syncthreads();

    for (int it = 0; it < NT; ++it) {
        const int k0  = kstart + it * 64;
        const int cur = it & 1;
        const bool more = (it + 1 < NT);

        // a) mask for tile t
        f32x4 mv4[4];
        #pragma unroll
        for (int kt = 0; kt < 4; ++kt)
            mv4[kt] = *reinterpret_cast<const f32x4*>(&mk[k0 + kt * 16 + 4 * lg]);

        // b) next K tile + current V tile -> regs (latency hidden by compute)
        if (more) loadK(k0 + 64);
        loadV(k0);

        // c) QK(t) from LDS
        const char* Kb = Kl[cur];
        f32x4 accs[4];
        __builtin_amdgcn_s_setprio(1);
        #pragma unroll
        for (int kt = 0; kt < 4; ++kt) {
            const int r = kt * 16 + lm;
            const bf16x8 kf0 = *reinterpret_cast<const bf16x8*>(Kb + r * RS + lg * 16);
            const bf16x8 kf1 = *reinterpret_cast<const bf16x8*>(Kb + r * RS + (lg + 4) * 16);
            f32x4 z = f32x4{0.f, 0.f, 0.f, 0.f};
            z = __builtin_amdgcn_mfma_f32_16x16x32_bf16(kf0, qf0, z, 0, 0, 0);
            z = __builtin_amdgcn_mfma_f32_16x16x32_bf16(kf1, qf1, z, 0, 0, 0);
            accs[kt] = z;
        }
        __builtin_amdgcn_s_setprio(0);

        // d) deferred: rescale cacc + PV(t-1) from Vl[(t-1)&1]
        if (it > 0) {
            const char* Vb = Vl[(it - 1) & 1];
            #pragma unroll
            for (int r = 0; r < 4; ++r) {
                const float sr = __shfl(scale_prev, lg * 4 + r);
                #pragma unroll
                for (int vt = 0; vt < 4; ++vt) cacc[vt][r] *= sr;
            }
            __builtin_amdgcn_s_setprio(1);
            #pragma unroll
            for (int kt = 0; kt < 4; ++kt)
                #pragma unroll
                for (int vt = 0; vt < 4; ++vt) {
                    const bf16x4 vfr = *reinterpret_cast<const bf16x4*>(
                        Vb + (vt * 16 + lm) * RS + (kt * 16 + lg * 4) * 2);
                    cacc[vt] = __builtin_amdgcn_mfma_f32_16x16x16bf16_1k(
                        pa_prev[kt], vfr, cacc[vt], 0, 0, 0);
                }
            __builtin_amdgcn_s_setprio(0);
        }

        // e) softmax(t) in log2 units (per-lane q = lm)
        float p[4][4];
        float tmax = -3.0e38f;
        #pragma unroll
        for (int kt = 0; kt < 4; ++kt)
            #pragma unroll
            for (int r = 0; r < 4; ++r) {
                p[kt][r] = accs[kt][r] + mv4[kt][r];
                tmax = fmaxf(tmax, p[kt][r]);
            }
        tmax = fmaxf(tmax, __shfl_xor(tmax, 16));
        tmax = fmaxf(tmax, __shfl_xor(tmax, 32));
        const float mnew  = fmaxf(m, tmax);
        const float sc_t  = exp2f(m - mnew);
        float psum = 0.f;
        #pragma unroll
        for (int kt = 0; kt < 4; ++kt)
            #pragma unroll
            for (int r = 0; r < 4; ++r) { p[kt][r] = exp2f(p[kt][r] - mnew); psum += p[kt][r]; }
        psum += __shfl_xor(psum, 16);
        psum += __shfl_xor(psum, 32);
        l = l * sc_t + psum;
        m = mnew;

        // f) pack P(t) with software RNE (cvt_pk asm is biased — r8/r9 lesson)
        #pragma unroll
        for (int kt = 0; kt < 4; ++kt) {
            bf16x4 tt;
            tt[0] = f2bf(p[kt][0]); tt[1] = f2bf(p[kt][1]);
            tt[2] = f2bf(p[kt][2]); tt[3] = f2bf(p[kt][3]);
            pa_prev[kt] = tt;
        }
        scale_prev = sc_t;

        // g) stage next K + current V into LDS, h) barrier
        if (more) storeK(cur ^ 1);
        storeV(cur);
        __syncthreads();
    }

    // epilogue: finish the last deferred tile (V(NT-1) staged in Vl[(NT-1)&1])
    {
        const char* Vb = Vl[(NT - 1) & 1];
        #pragma unroll
        for (int r = 0; r < 4; ++r) {
            const float sr = __shfl(scale_prev, lg * 4 + r);
            #pragma unroll
            for (int vt = 0; vt < 4; ++vt) cacc[vt][r] *= sr;
        }
        #pragma unroll
        for (int kt = 0; kt < 4; ++kt)
            #pragma unroll
            for (int vt = 0; vt < 4; ++vt) {
                const bf16x4 vfr = *reinterpret_cast<const bf16x4*>(
                    Vb + (vt * 16 + lm) * RS + (kt * 16 + lg * 4) * 2);
                cacc[vt] = __builtin_amdgcn_mfma_f32_16x16x16bf16_1k(
                    pa_prev[kt], vfr, cacc[vt], 0, 0, 0);
            }
    }

    float* ctxp = (s == 0) ? ctx0 : ctx1;
    #pragma unroll
    for (int r = 0; r < 4; ++r) {
        float* orow = ctxp + ((size_t)b * N_ + q0 + lg * 4 + r) * HID + h * HD;
        #pragma unroll
        for (int vt = 0; vt < 4; ++vt) orow[vt * 16 + lm] = cacc[vt][r];
    }
    if (lane < 16) {
        const size_t idx = (size_t)s * (B_ * NH * N_) + bh * N_ + q0 + lane;
        m_part[idx] = m;
        l_part[idx] = l;
    }
}

// ---------------------------------------------------------------------------
// K2b: merge NSPLIT=2 partials (log2-unit maxima).  grid 12288 x 256.
// ---------------------------------------------------------------------------
__global__ __launch_bounds__(256) void merge_kernel(
    float* __restrict__ ctx0, const float* __restrict__ ctx1,
    const float* __restrict__ m_part, const float* __restrict__ l_part,
    float* __restrict__ m_ws, float* __restrict__ l_ws)
{
    const int gid  = blockIdx.x * 256 + threadIdx.x;
    const int row  = gid >> 6;
    const int lane = gid & 63;
    const int bh = row >> 11;
    const int n  = row & 2047;
    const int b  = bh / NH, h = bh % NH;
    constexpr int PS = B_ * NH * N_;

    const float m0 = m_part[row], m1 = m_part[PS + row];
    const float l0 = l_part[row], l1 = l_part[PS + row];
    const float M  = fmaxf(m0, m1);
    const float w0 = exp2f(m0 - M), w1 = exp2f(m1 - M);
    const float L  = w0 * l0 + w1 * l1;
    const float invL = 1.f / L;

    const size_t cidx = ((size_t)b * N_ + n) * HID + h * HD + lane;
    ctx0[cidx] = (w0 * ctx0[cidx] + w1 * ctx1[cidx]) * invL;

    if (lane == 0) { m_ws[row] = M; l_ws[row] = L; }
}

// ---------------------------------------------------------------------------
// K3: attn_weights = sum_h probs / 12.  grid (N/16, N/256, B), block 256.
// Heads unrolled x2: two independent load->MFMA->exp chains in flight.
// ---------------------------------------------------------------------------
__global__ __launch_bounds__(256) void attnw_kernel(
    const short* __restrict__ qb, const short* __restrict__ kbm,
    const float* __restrict__ mks, const float* __restrict__ m_ws,
    const float* __restrict__ l_ws, float* __restrict__ out_attn)
{
    const int qt = blockIdx.x, ct = blockIdx.y, b = blockIdx.z;
    const int lane = threadIdx.x & 63;
    const int wave = threadIdx.x >> 6;
    const int lg = lane >> 4, lm = lane & 15;
    const int q0 = qt * 16;
    const int kbase = ct * 256 + wave * 64;

    float mv[4];
    #pragma unroll
    for (int kt = 0; kt < 4; ++kt) mv[kt] = mks[(size_t)b * N_ + kbase + kt * 16 + lm];

    f32x4 accw[4];
    #pragma unroll
    for (int kt = 0; kt < 4; ++kt) accw[kt] = f32x4{0.f, 0.f, 0.f, 0.f};

    #pragma unroll 2
    for (int h = 0; h < NH; ++h) {
        const size_t bh = (size_t)(b * NH + h);
        const short* qp = qb + (bh * N_ + q0) * HD;
        const bf16x8 qf0 = *reinterpret_cast<const bf16x8*>(qp + lm * HD + lg * 8);
        const bf16x8 qf1 = *reinterpret_cast<const bf16x8*>(qp + lm * HD + lg * 8 + 32);
        const short* kp = kbm + bh * N_ * HD;
        float mr[4], il[4];
        #pragma unroll
        for (int r = 0; r < 4; ++r) {
            mr[r] = m_ws[bh * N_ + q0 + lg * 4 + r];
            il[r] = 1.f / l_ws[bh * N_ + q0 + lg * 4 + r];
        }
        #pragma unroll
        for (int kt = 0; kt < 4; ++kt) {
            const short* kr = kp + (size_t)(kbase + kt * 16 + lm) * HD + lg * 8;
            const bf16x8 kf0 = *reinterpret_cast<const bf16x8*>(kr);
            const bf16x8 kf1 = *reinterpret_cast<const bf16x8*>(kr + 32);
            f32x4 z = f32x4{0.f, 0.f, 0.f, 0.f};
            z = __builtin_amdgcn_mfma_f32_16x16x32_bf16(qf0, kf0, z, 0, 0, 0);
            z = __builtin_amdgcn_mfma_f32_16x16x32_bf16(qf1, kf1, z, 0, 0, 0);
            #pragma unroll
            for (int r = 0; r < 4; ++r)
                accw[kt][r] += exp2f(z[r] + mv[kt] - mr[r]) * il[r];
        }
    }
    #pragma unroll
    for (int kt = 0; kt < 4; ++kt)
        #pragma unroll
        for (int r = 0; r < 4; ++r)
            out_attn[((size_t)b * N_ + q0 + lg * 4 + r) * N_ + kbase + kt * 16 + lm]
                = accw[kt][r] * (1.0f / 12.0f);
}

// ---------------------------------------------------------------------------
extern "C" void kernel_launch(void* const* d_in, const int* in_sizes, int n_in,
                              void* d_out, int out_size, void* d_ws, size_t ws_size,
                              hipStream_t stream) {
    (void)in_sizes; (void)n_in; (void)out_size;
    const float* s1   = (const float*)d_in[0];
    const float* s2   = (const float*)d_in[1];
    const float* mask = (const float*)d_in[2];
    const float* Wq   = (const float*)d_in[3];
    const float* bq   = (const float*)d_in[4];
    const float* Wk   = (const float*)d_in[5];
    const float* bk   = (const float*)d_in[6];
    const float* Wv   = (const float*)d_in[7];
    const float* bv   = (const float*)d_in[8];

    float* out_ctx  = (float*)d_out;
    float* out_attn = out_ctx + (size_t)B_ * N_ * HID;

    const size_t xlen = (size_t)B_ * N_ * 1536;     // hi|lo shorts per tensor
    const size_t qkv  = (size_t)B_ * NH * N_ * HD;
    const size_t rows = (size_t)B_ * NH * N_;
    short* X1   = (short*)d_ws;
    short* X2   = X1 + xlen;
    short* WT   = X2 + xlen;
    short* qb   = WT + (size_t)3 * HID * HID;
    short* kbm  = qb + qkv;
    short* vtb  = kbm + qkv;
    float* ctx1 = (float*)(vtb + qkv);
    float* m_part = ctx1 + (size_t)B_ * N_ * HID;
    float* l_part = m_part + NSPLIT * rows;
    float* m_ws   = l_part + NSPLIT * rows;
    float* l_ws   = m_ws + rows;
    float* mks    = l_ws + rows;
    const size_t need = (size_t)((char*)(mks + (size_t)B_ * N_) - (char*)d_ws);
    if (ws_size < need) return;

    prep_x<<<6148, 256, 0, stream>>>(s1, s2, mask, X1, X2, mks);
    prep_w<<<dim3(12, 12, 3), 256, 0, stream>>>(Wq, Wk, Wv, WT);
    proj_mfma<<<dim3(32, 12, 3), 256, 0, stream>>>(X1, X2, WT, bq, bk, bv, qb, kbm, vtb);
    flash_kernel<<<dim3(N_ / 64, NH, B_ * NSPLIT), 256, 0, stream>>>(
        qb, kbm, vtb, mks, out_ctx, ctx1, m_part, l_part);
    merge_kernel<<<(B_ * N_ * HID) / 256, 256, 0, stream>>>(
        out_ctx, ctx1, m_part, l_part, m_ws, l_ws);
    attnw_kernel<<<dim3(N_ / 16, N_ / 256, B_), 256, 0, stream>>>(
        qb, kbm, mks, m_ws, l_ws, out_attn);
}

// Round 12
// 310.309 us; speedup vs baseline: 1.6742x; 1.1744x over previous
//
#include <hip/hip_runtime.h>
#include <stdint.h>

// Cross-attention forward: B=2, N1=N2=2048, HID=768, 12 heads x 64.
// Round 12: r11 + ONE change — attnw restructured like flash: grid
// (N/64, N/64, B), 4 waves share a 64-key K-tile staged in LDS (padded,
// double-buffered over the head loop), each wave owns 16 q-rows. K per-block
// traffic 384KB/16rows -> 96KB/64rows (16x amortization), frag reads from LDS.

typedef __attribute__((ext_vector_type(8))) short bf16x8;
typedef __attribute__((ext_vector_type(4))) short bf16x4;
typedef __attribute__((ext_vector_type(4))) float f32x4;

constexpr int B_  = 2;
constexpr int N_  = 2048;   // N1 == N2
constexpr int HID = 768;
constexpr int NH  = 12;
constexpr int HD  = 64;
constexpr int RS  = 144;    // LDS row stride bytes: 128 data + 16 pad
constexpr int NSPLIT = 2;
constexpr int KSPAN  = N_ / NSPLIT;   // 1024
constexpr int NT     = KSPAN / 64;    // 16 tiles per flash block
constexpr float L2E = 1.4426950408889634f;   // log2(e)

__device__ __forceinline__ short f2bf(float f) {   // RNE float->bf16
    uint32_t u = __builtin_bit_cast(uint32_t, f);
    u = (u + 0x7fffu + ((u >> 16) & 1u)) >> 16;
    return (short)u;
}

// ---------------------------------------------------------------------------
// P0a: X -> (hi|lo) bf16 rows of 1536.  hi = trunc-bf16(x), lo = RNE(x-hi).
// Blocks >= 6144 prescale mask by log2e.
// ---------------------------------------------------------------------------
__global__ __launch_bounds__(256) void prep_x(
    const float* __restrict__ s1, const float* __restrict__ s2,
    const float* __restrict__ mask,
    short* __restrict__ X1, short* __restrict__ X2, float* __restrict__ mks)
{
    const int PT = (B_ * N_ * HID) / 4;       // 786432 quads per tensor
    if (blockIdx.x >= 6144) {
        const int idx = (blockIdx.x - 6144) * 256 + threadIdx.x;   // < 1024
        const float4 mv = *reinterpret_cast<const float4*>(&mask[idx * 4]);
        *reinterpret_cast<float4*>(&mks[idx * 4]) =
            make_float4(mv.x * L2E, mv.y * L2E, mv.z * L2E, mv.w * L2E);
        return;
    }
    int i = blockIdx.x * 256 + threadIdx.x;
    const float* S; short* X;
    if (i < PT) { S = s1; X = X1; } else { S = s2; X = X2; i -= PT; }
    const int e   = i * 4;
    const int row = e / HID;
    const int col = e - row * HID;
    const float4 v = *reinterpret_cast<const float4*>(&S[e]);
    float vs[4] = {v.x, v.y, v.z, v.w};
    short4 hi, lo;
    short* hp = &hi.x; short* lp = &lo.x;
    #pragma unroll
    for (int j = 0; j < 4; ++j) {
        const uint32_t u = __builtin_bit_cast(uint32_t, vs[j]);
        hp[j] = (short)(u >> 16);
        const float hif = __builtin_bit_cast(float, u & 0xffff0000u);
        lp[j] = f2bf(vs[j] - hif);
    }
    short* dst = X + (size_t)row * 1536 + col;
    *reinterpret_cast<short4*>(dst)       = hi;
    *reinterpret_cast<short4*>(dst + 768) = lo;
}

// ---------------------------------------------------------------------------
// P0b: W [k][n] fp32 -> WT [n][k] bf16 (3 matrices).  grid (12,12,3) x 256.
// ---------------------------------------------------------------------------
__global__ __launch_bounds__(256) void prep_w(
    const float* __restrict__ Wq, const float* __restrict__ Wk,
    const float* __restrict__ Wv, short* __restrict__ WT)
{
    const int z = blockIdx.z;
    const float* W = (z == 0) ? Wq : (z == 1) ? Wk : Wv;
    short* O = WT + (size_t)z * HID * HID;
    __shared__ short Tl[64][66];
    const int k0 = blockIdx.x * 64, n0 = blockIdx.y * 64;
    const int t = threadIdx.x;
    const int rr = t >> 4, cc = (t & 15) * 4;
    #pragma unroll
    for (int i = 0; i < 4; ++i) {
        const int row = i * 16 + rr;
        const float4 w = *reinterpret_cast<const float4*>(&W[(size_t)(k0 + row) * HID + n0 + cc]);
        Tl[cc + 0][row] = f2bf(w.x);
        Tl[cc + 1][row] = f2bf(w.y);
        Tl[cc + 2][row] = f2bf(w.z);
        Tl[cc + 3][row] = f2bf(w.w);
    }
    __syncthreads();
    #pragma unroll
    for (int i = 0; i < 4; ++i) {
        const int n = i * 16 + rr;
        short4 o;
        o.x = Tl[n][cc + 0]; o.y = Tl[n][cc + 1];
        o.z = Tl[n][cc + 2]; o.w = Tl[n][cc + 3];
        *reinterpret_cast<short4*>(&O[(size_t)(n0 + n) * HID + k0 + cc]) = o;
    }
}

// ---------------------------------------------------------------------------
// K1: proj GEMM (bf16 MFMA, hi/lo split).  grid (32, 12, 3), block 256.
// Tile 128x64, BK=64. Reg-staged dbuf padded LDS. q,k: KSTEPS=24 (hi then lo,
// W repeats via ks%12); v: 12 (hi only).
// which=0: q*(0.125*log2e) -> qb; 1: k -> kbm; 2: v -> vtb [bh][d][n].
// ---------------------------------------------------------------------------
__global__ __launch_bounds__(256) void proj_mfma(
    const short* __restrict__ X1, const short* __restrict__ X2,
    const short* __restrict__ WT,
    const float* __restrict__ bq, const float* __restrict__ bk,
    const float* __restrict__ bv,
    short* __restrict__ qb, short* __restrict__ kbm, short* __restrict__ vtb)
{
    const int which = blockIdx.z;
    const char* Xb = (const char*)((which == 0) ? X1 : X2);        // row 3072 B
    const char* Wb = (const char*)(WT + (size_t)which * HID * HID); // row 1536 B
    const float* bias = (which == 0) ? bq : (which == 1) ? bk : bv;
    const int m0 = blockIdx.x * 128;
    const int n0 = blockIdx.y * 64;
    const int t = threadIdx.x;
    const int lane = t & 63;
    const int lg = lane >> 4, lm = lane & 15;
    const int wave = t >> 6;
    const int wr = wave >> 1, wc = wave & 1;

    __shared__ __align__(16) char Al[2][128 * RS];
    __shared__ __align__(16) char Bl[2][64 * RS];

    const int KSTEPS = (which == 2) ? 12 : 24;

    f32x4 acc[4][2];
    #pragma unroll
    for (int mt = 0; mt < 4; ++mt)
        #pragma unroll
        for (int nt = 0; nt < 2; ++nt) acc[mt][nt] = f32x4{0.f, 0.f, 0.f, 0.f};

    int4 ra[4], rb[2];
    auto loadAB = [&](int ks) {
        const int ka = ks * 128;            // byte col into X row (hi then lo)
        const int kw = (ks % 12) * 128;     // byte col into WT row (W repeats)
        #pragma unroll
        for (int u = 0; u < 4; ++u) {
            const int c = u * 256 + t;      // row=c>>3, j=c&7
            ra[u] = *reinterpret_cast<const int4*>(
                Xb + (size_t)(m0 + (c >> 3)) * 3072 + ka + (c & 7) * 16);
        }
        #pragma unroll
        for (int u = 0; u < 2; ++u) {
            const int c = u * 256 + t;
            rb[u] = *reinterpret_cast<const int4*>(
                Wb + (size_t)(n0 + (c >> 3)) * 1536 + kw + (c & 7) * 16);
        }
    };
    auto storeAB = [&](int buf) {
        #pragma unroll
        for (int u = 0; u < 4; ++u) {
            const int c = u * 256 + t;      // byte = row*RS + j*16
            *reinterpret_cast<int4*>(&Al[buf][c * 16 + (c >> 3) * 16]) = ra[u];
        }
        #pragma unroll
        for (int u = 0; u < 2; ++u) {
            const int c = u * 256 + t;
            *reinterpret_cast<int4*>(&Bl[buf][c * 16 + (c >> 3) * 16]) = rb[u];
        }
    };

    loadAB(0);
    storeAB(0);
    __syncthreads();

    for (int ks = 0; ks < KSTEPS; ++ks) {
        const bool more = (ks + 1 < KSTEPS);
        if (more) loadAB(ks + 1);
        const char* Ab = Al[ks & 1];
        const char* Bb = Bl[ks & 1];
        #pragma unroll
        for (int ksub = 0; ksub < 2; ++ksub) {
            const int jj = ksub * 4 + lg;
            bf16x8 a[4], bb[2];
            #pragma unroll
            for (int mt = 0; mt < 4; ++mt) {
                const int r = wr * 64 + mt * 16 + lm;
                a[mt] = *reinterpret_cast<const bf16x8*>(Ab + r * RS + jj * 16);
            }
            #pragma unroll
            for (int nt = 0; nt < 2; ++nt) {
                const int r = wc * 32 + nt * 16 + lm;
                bb[nt] = *reinterpret_cast<const bf16x8*>(Bb + r * RS + jj * 16);
            }
            __builtin_amdgcn_s_setprio(1);
            #pragma unroll
            for (int mt = 0; mt < 4; ++mt)
                #pragma unroll
                for (int nt = 0; nt < 2; ++nt)
                    acc[mt][nt] = __builtin_amdgcn_mfma_f32_16x16x32_bf16(
                        a[mt], bb[nt], acc[mt][nt], 0, 0, 0);
            __builtin_amdgcn_s_setprio(0);
        }
        if (more) storeAB((ks + 1) & 1);
        __syncthreads();
    }

    const int b = m0 >> 11;
    const int head = blockIdx.y;
    const size_t bh = (size_t)(b * NH + head);

    if (which != 2) {
        const float sc = (which == 0) ? (0.125f * L2E) : 1.0f;
        short* dst = (which == 0) ? qb : kbm;
        #pragma unroll
        for (int mt = 0; mt < 4; ++mt)
            #pragma unroll
            for (int nt = 0; nt < 2; ++nt) {
                const int dd = wc * 32 + nt * 16 + lm;
                const float bi = bias[n0 + dd];
                #pragma unroll
                for (int r = 0; r < 4; ++r) {
                    const int m = m0 + wr * 64 + mt * 16 + 4 * lg + r;
                    const int n = m & 2047;
                    dst[(bh * N_ + n) * HD + dd] = f2bf((acc[mt][nt][r] + bi) * sc);
                }
            }
    } else {
        short* Ct = (short*)Al[0];           // [64 d][128 m] bf16
        #pragma unroll
        for (int mt = 0; mt < 4; ++mt)
            #pragma unroll
            for (int nt = 0; nt < 2; ++nt) {
                const int dd = wc * 32 + nt * 16 + lm;
                const float bi = bias[n0 + dd];
                #pragma unroll
                for (int r = 0; r < 4; ++r) {
                    const int ml = wr * 64 + mt * 16 + 4 * lg + r;
                    Ct[dd * 128 + ml] = f2bf(acc[mt][nt][r] + bi);
                }
            }
        __syncthreads();
        const int d = t >> 2, seg = t & 3;
        const short* src = Ct + d * 128 + seg * 32;
        short* dv = vtb + (bh * HD + d) * N_ + (m0 & 2047) + seg * 32;
        #pragma unroll
        for (int u = 0; u < 4; ++u)
            *reinterpret_cast<int4*>(dv + u * 8) = *reinterpret_cast<const int4*>(src + u * 8);
    }
}

// ---------------------------------------------------------------------------
// K2: split-K flash, deferred-PV + LDS-staged K and V^T (r11, passing).
// ---------------------------------------------------------------------------
__global__ __launch_bounds__(256) void flash_kernel(
    const short* __restrict__ qb, const short* __restrict__ kbm,
    const short* __restrict__ vtb, const float* __restrict__ mks,
    float* __restrict__ ctx0, float* __restrict__ ctx1,
    float* __restrict__ m_part, float* __restrict__ l_part)
{
    const int qt = blockIdx.x, h = blockIdx.y;
    const int b = blockIdx.z / NSPLIT, s = blockIdx.z % NSPLIT;
    const int t = threadIdx.x;
    const int lane = t & 63;
    const int wave = __builtin_amdgcn_readfirstlane(t >> 6);
    const int lg = lane >> 4, lm = lane & 15;
    const int q0 = qt * 64 + wave * 16;
    const int kstart = s * KSPAN;

    __shared__ __align__(16) char Kl[2][64 * RS];   // K rows (keys) x 128B
    __shared__ __align__(16) char Vl[2][64 * RS];   // V^T rows (d)   x 128B

    const size_t bh = (size_t)(b * NH + h);
    const short* qp  = qb  + (bh * N_ + q0) * HD;
    const char*  kpb = (const char*)(kbm + bh * N_ * HD);   // row 128 B
    const char*  vpb = (const char*)(vtb + bh * HD * N_);   // row N_*2 B
    const float* mk  = mks + (size_t)b * N_;

    const bf16x8 qf0 = *reinterpret_cast<const bf16x8*>(qp + lm * HD + lg * 8);
    const bf16x8 qf1 = *reinterpret_cast<const bf16x8*>(qp + lm * HD + lg * 8 + 32);

    f32x4 cacc[4];
    #pragma unroll
    for (int vt = 0; vt < 4; ++vt) cacc[vt] = f32x4{0.f, 0.f, 0.f, 0.f};
    float m = -1e30f, l = 0.f;
    float scale_prev = 1.f;
    bf16x4 pa_prev[4];

    int4 rk[2], rv[2];
    auto loadK = [&](int krow) {
        #pragma unroll
        for (int u = 0; u < 2; ++u) {
            const int c = u * 256 + t;
            rk[u] = *reinterpret_cast<const int4*>(
                kpb + (size_t)(krow + (c >> 3)) * 128 + (c & 7) * 16);
        }
    };
    auto storeK = [&](int buf) {
        #pragma unroll
        for (int u = 0; u < 2; ++u) {
            const int c = u * 256 + t;
            *reinterpret_cast<int4*>(&Kl[buf][c * 16 + (c >> 3) * 16]) = rk[u];
        }
    };
    auto loadV = [&](int k0) {
        #pragma unroll
        for (int u = 0; u < 2; ++u) {
            const int c = u * 256 + t;
            rv[u] = *reinterpret_cast<const int4*>(
                vpb + (size_t)(c >> 3) * (N_ * 2) + (size_t)k0 * 2 + (c & 7) * 16);
        }
    };
    auto storeV = [&](int buf) {
        #pragma unroll
        for (int u = 0; u < 2; ++u) {
            const int c = u * 256 + t;
            *reinterpret_cast<int4*>(&Vl[buf][c * 16 + (c >> 3) * 16]) = rv[u];
        }
    };

    loadK(kstart);
    storeK(0);
    __syncthreads();

    for (int it = 0; it < NT; ++it) {
        const int k0  = kstart + it * 64;
        const int cur = it & 1;
        const bool more = (it + 1 < NT);

        f32x4 mv4[4];
        #pragma unroll
        for (int kt = 0; kt < 4; ++kt)
            mv4[kt] = *reinterpret_cast<const f32x4*>(&mk[k0 + kt * 16 + 4 * lg]);

        if (more) loadK(k0 + 64);
        loadV(k0);

        const char* Kb = Kl[cur];
        f32x4 accs[4];
        __builtin_amdgcn_s_setprio(1);
        #pragma unroll
        for (int kt = 0; kt < 4; ++kt) {
            const int r = kt * 16 + lm;
            const bf16x8 kf0 = *reinterpret_cast<const bf16x8*>(Kb + r * RS + lg * 16);
            const bf16x8 kf1 = *reinterpret_cast<const bf16x8*>(Kb + r * RS + (lg + 4) * 16);
            f32x4 z = f32x4{0.f, 0.f, 0.f, 0.f};
            z = __builtin_amdgcn_mfma_f32_16x16x32_bf16(kf0, qf0, z, 0, 0, 0);
            z = __builtin_amdgcn_mfma_f32_16x16x32_bf16(kf1, qf1, z, 0, 0, 0);
            accs[kt] = z;
        }
        __builtin_amdgcn_s_setprio(0);

        if (it > 0) {
            const char* Vb = Vl[(it - 1) & 1];
            #pragma unroll
            for (int r = 0; r < 4; ++r) {
                const float sr = __shfl(scale_prev, lg * 4 + r);
                #pragma unroll
                for (int vt = 0; vt < 4; ++vt) cacc[vt][r] *= sr;
            }
            __builtin_amdgcn_s_setprio(1);
            #pragma unroll
            for (int kt = 0; kt < 4; ++kt)
                #pragma unroll
                for (int vt = 0; vt < 4; ++vt) {
                    const bf16x4 vfr = *reinterpret_cast<const bf16x4*>(
                        Vb + (vt * 16 + lm) * RS + (kt * 16 + lg * 4) * 2);
                    cacc[vt] = __builtin_amdgcn_mfma_f32_16x16x16bf16_1k(
                        pa_prev[kt], vfr, cacc[vt], 0, 0, 0);
                }
            __builtin_amdgcn_s_setprio(0);
        }

        float p[4][4];
        float tmax = -3.0e38f;
        #pragma unroll
        for (int kt = 0; kt < 4; ++kt)
            #pragma unroll
            for (int r = 0; r < 4; ++r) {
                p[kt][r] = accs[kt][r] + mv4[kt][r];
                tmax = fmaxf(tmax, p[kt][r]);
            }
        tmax = fmaxf(tmax, __shfl_xor(tmax, 16));
        tmax = fmaxf(tmax, __shfl_xor(tmax, 32));
        const float mnew  = fmaxf(m, tmax);
        const float sc_t  = exp2f(m - mnew);
        float psum = 0.f;
        #pragma unroll
        for (int kt = 0; kt < 4; ++kt)
            #pragma unroll
            for (int r = 0; r < 4; ++r) { p[kt][r] = exp2f(p[kt][r] - mnew); psum += p[kt][r]; }
        psum += __shfl_xor(psum, 16);
        psum += __shfl_xor(psum, 32);
        l = l * sc_t + psum;
        m = mnew;

        #pragma unroll
        for (int kt = 0; kt < 4; ++kt) {
            bf16x4 tt;
            tt[0] = f2bf(p[kt][0]); tt[1] = f2bf(p[kt][1]);
            tt[2] = f2bf(p[kt][2]); tt[3] = f2bf(p[kt][3]);
            pa_prev[kt] = tt;
        }
        scale_prev = sc_t;

        if (more) storeK(cur ^ 1);
        storeV(cur);
        __syncthreads();
    }

    {
        const char* Vb = Vl[(NT - 1) & 1];
        #pragma unroll
        for (int r = 0; r < 4; ++r) {
            const float sr = __shfl(scale_prev, lg * 4 + r);
            #pragma unroll
            for (int vt = 0; vt < 4; ++vt) cacc[vt][r] *= sr;
        }
        #pragma unroll
        for (int kt = 0; kt < 4; ++kt)
            #pragma unroll
            for (int vt = 0; vt < 4; ++vt) {
                const bf16x4 vfr = *reinterpret_cast<const bf16x4*>(
                    Vb + (vt * 16 + lm) * RS + (kt * 16 + lg * 4) * 2);
                cacc[vt] = __builtin_amdgcn_mfma_f32_16x16x16bf16_1k(
                    pa_prev[kt], vfr, cacc[vt], 0, 0, 0);
            }
    }

    float* ctxp = (s == 0) ? ctx0 : ctx1;
    #pragma unroll
    for (int r = 0; r < 4; ++r) {
        float* orow = ctxp + ((size_t)b * N_ + q0 + lg * 4 + r) * HID + h * HD;
        #pragma unroll
        for (int vt = 0; vt < 4; ++vt) orow[vt * 16 + lm] = cacc[vt][r];
    }
    if (lane < 16) {
        const size_t idx = (size_t)s * (B_ * NH * N_) + bh * N_ + q0 + lane;
        m_part[idx] = m;
        l_part[idx] = l;
    }
}

// ---------------------------------------------------------------------------
// K2b: merge NSPLIT=2 partials (log2-unit maxima).  grid 12288 x 256.
// ---------------------------------------------------------------------------
__global__ __launch_bounds__(256) void merge_kernel(
    float* __restrict__ ctx0, const float* __restrict__ ctx1,
    const float* __restrict__ m_part, const float* __restrict__ l_part,
    float* __restrict__ m_ws, float* __restrict__ l_ws)
{
    const int gid  = blockIdx.x * 256 + threadIdx.x;
    const int row  = gid >> 6;
    const int lane = gid & 63;
    const int bh = row >> 11;
    const int n  = row & 2047;
    const int b  = bh / NH, h = bh % NH;
    constexpr int PS = B_ * NH * N_;

    const float m0 = m_part[row], m1 = m_part[PS + row];
    const float l0 = l_part[row], l1 = l_part[PS + row];
    const float M  = fmaxf(m0, m1);
    const float w0 = exp2f(m0 - M), w1 = exp2f(m1 - M);
    const float L  = w0 * l0 + w1 * l1;
    const float invL = 1.f / L;

    const size_t cidx = ((size_t)b * N_ + n) * HID + h * HD + lane;
    ctx0[cidx] = (w0 * ctx0[cidx] + w1 * ctx1[cidx]) * invL;

    if (lane == 0) { m_ws[row] = M; l_ws[row] = L; }
}

// ---------------------------------------------------------------------------
// K3: attn_weights = sum_h probs / 12.  grid (N/64, N/64, B), block 256.
// Flash-style: 4 waves share one 64-key K-tile staged in padded LDS
// (double-buffered over the head loop); wave w owns q-rows qt*64+w*16..+15.
// ---------------------------------------------------------------------------
__global__ __launch_bounds__(256) void attnw_kernel(
    const short* __restrict__ qb, const short* __restrict__ kbm,
    const float* __restrict__ mks, const float* __restrict__ m_ws,
    const float* __restrict__ l_ws, float* __restrict__ out_attn)
{
    const int qt = blockIdx.x, ct = blockIdx.y, b = blockIdx.z;
    const int t = threadIdx.x;
    const int lane = t & 63;
    const int wave = __builtin_amdgcn_readfirstlane(t >> 6);
    const int lg = lane >> 4, lm = lane & 15;
    const int q0 = qt * 64 + wave * 16;
    const int kbase = ct * 64;

    __shared__ __align__(16) char Kl[2][64 * RS];

    float mv[4];
    #pragma unroll
    for (int kt = 0; kt < 4; ++kt) mv[kt] = mks[(size_t)b * N_ + kbase + kt * 16 + lm];

    f32x4 accw[4];
    #pragma unroll
    for (int kt = 0; kt < 4; ++kt) accw[kt] = f32x4{0.f, 0.f, 0.f, 0.f};

    int4 rk[2];
    auto loadK = [&](int h) {
        const char* kpb = (const char*)(kbm + ((size_t)(b * NH + h) * N_) * HD);
        #pragma unroll
        for (int u = 0; u < 2; ++u) {
            const int c = u * 256 + t;
            rk[u] = *reinterpret_cast<const int4*>(
                kpb + (size_t)(kbase + (c >> 3)) * 128 + (c & 7) * 16);
        }
    };
    auto storeK = [&](int buf) {
        #pragma unroll
        for (int u = 0; u < 2; ++u) {
            const int c = u * 256 + t;
            *reinterpret_cast<int4*>(&Kl[buf][c * 16 + (c >> 3) * 16]) = rk[u];
        }
    };

    loadK(0);
    storeK(0);
    __syncthreads();

    for (int h = 0; h < NH; ++h) {
        const bool more = (h + 1 < NH);
        if (more) loadK(h + 1);            // global->reg during compute

        const size_t bh = (size_t)(b * NH + h);
        const short* qp = qb + (bh * N_ + q0) * HD;
        const bf16x8 qf0 = *reinterpret_cast<const bf16x8*>(qp + lm * HD + lg * 8);
        const bf16x8 qf1 = *reinterpret_cast<const bf16x8*>(qp + lm * HD + lg * 8 + 32);
        float mr[4], il[4];
        #pragma unroll
        for (int r = 0; r < 4; ++r) {
            mr[r] = m_ws[bh * N_ + q0 + lg * 4 + r];
            il[r] = 1.f / l_ws[bh * N_ + q0 + lg * 4 + r];
        }
        const char* Kb = Kl[h & 1];
        __builtin_amdgcn_s_setprio(1);
        #pragma unroll
        for (int kt = 0; kt < 4; ++kt) {
            const int r = kt * 16 + lm;
            const bf16x8 kf0 = *reinterpret_cast<const bf16x8*>(Kb + r * RS + lg * 16);
            const bf16x8 kf1 = *reinterpret_cast<const bf16x8*>(Kb + r * RS + (lg + 4) * 16);
            f32x4 z = f32x4{0.f, 0.f, 0.f, 0.f};
            z = __builtin_amdgcn_mfma_f32_16x16x32_bf16(qf0, kf0, z, 0, 0, 0);
            z = __builtin_amdgcn_mfma_f32_16x16x32_bf16(qf1, kf1, z, 0, 0, 0);
            #pragma unroll
            for (int rr = 0; rr < 4; ++rr)
                accw[kt][rr] += exp2f(z[rr] + mv[kt] - mr[rr]) * il[rr];
        }
        __builtin_amdgcn_s_setprio(0);

        if (more) storeK((h + 1) & 1);     // other buffer: safe before barrier
        __syncthreads();
    }

    #pragma unroll
    for (int kt = 0; kt < 4; ++kt)
        #pragma unroll
        for (int r = 0; r < 4; ++r)
            out_attn[((size_t)b * N_ + q0 + lg * 4 + r) * N_ + kbase + kt * 16 + lm]
                = accw[kt][r] * (1.0f / 12.0f);
}

// ---------------------------------------------------------------------------
extern "C" void kernel_launch(void* const* d_in, const int* in_sizes, int n_in,
                              void* d_out, int out_size, void* d_ws, size_t ws_size,
                              hipStream_t stream) {
    (void)in_sizes; (void)n_in; (void)out_size;
    const float* s1   = (const float*)d_in[0];
    const float* s2   = (const float*)d_in[1];
    const float* mask = (const float*)d_in[2];
    const float* Wq   = (const float*)d_in[3];
    const float* bq   = (const float*)d_in[4];
    const float* Wk   = (const float*)d_in[5];
    const float* bk   = (const float*)d_in[6];
    const float* Wv   = (const float*)d_in[7];
    const float* bv   = (const float*)d_in[8];

    float* out_ctx  = (float*)d_out;
    float* out_attn = out_ctx + (size_t)B_ * N_ * HID;

    const size_t xlen = (size_t)B_ * N_ * 1536;     // hi|lo shorts per tensor
    const size_t qkv  = (size_t)B_ * NH * N_ * HD;
    const size_t rows = (size_t)B_ * NH * N_;
    short* X1   = (short*)d_ws;
    short* X2   = X1 + xlen;
    short* WT   = X2 + xlen;
    short* qb   = WT + (size_t)3 * HID * HID;
    short* kbm  = qb + qkv;
    short* vtb  = kbm + qkv;
    float* ctx1 = (float*)(vtb + qkv);
    float* m_part = ctx1 + (size_t)B_ * N_ * HID;
    float* l_part = m_part + NSPLIT * rows;
    float* m_ws   = l_part + NSPLIT * rows;
    float* l_ws   = m_ws + rows;
    float* mks    = l_ws + rows;
    const size_t need = (size_t)((char*)(mks + (size_t)B_ * N_) - (char*)d_ws);
    if (ws_size < need) return;

    prep_x<<<6148, 256, 0, stream>>>(s1, s2, mask, X1, X2, mks);
    prep_w<<<dim3(12, 12, 3), 256, 0, stream>>>(Wq, Wk, Wv, WT);
    proj_mfma<<<dim3(32, 12, 3), 256, 0, stream>>>(X1, X2, WT, bq, bk, bv, qb, kbm, vtb);
    flash_kernel<<<dim3(N_ / 64, NH, B_ * NSPLIT), 256, 0, stream>>>(
        qb, kbm, vtb, mks, out_ctx, ctx1, m_part, l_part);
    merge_kernel<<<(B_ * N_ * HID) / 256, 256, 0, stream>>>(
        out_ctx, ctx1, m_part, l_part, m_ws, l_ws);
    attnw_kernel<<<dim3(N_ / 64, N_ / 64, B_), 256, 0, stream>>>(
        qb, kbm, mks, m_ws, l_ws, out_attn);
}